// Round 5
// baseline (3169.805 us; speedup 1.0000x reference)
//
#include <hip/hip_runtime.h>

// Hetero-GNN: 5 layers of relu(segsum_temp(x)@Wt + segmean_inter(x)@Wi + x@Wr + b)
// (aggregation commuted past the matmuls).
//
// R5 structure: edges are counting-sorted ONCE into 64-destination buckets as
// packed ints (dl<<20 | src). Each layer = ONE kernel, one block per bucket:
//   phase 1: stream the bucket's edge list (coalesced), gather 8 feature rows
//            per wave-instr, ds_add_f32 into LDS accumulators (stride 33 = odd
//            -> ~2-way bank aliasing, free). In-degree counted in LDS.
//   phase 2: __syncthreads, per-node mini-GEMM reading broadcast inputs from
//            LDS (ds_read) and hot weights from global.
// This replaces the wave-per-destination serial gather (latency-bound, VGPR=24,
// VALU 43%) with an independent edge stream the compiler can pipeline.
// Assumes N <= 131072 (NB <= 2048) and N < 2^20 for packing (N=100k here).

#define DPB 64          // destinations per bucket (shift = 6)
#define SH 6
#define NBMAX 2048
#define SENT (DPB << 20)

// ---------------- build: hist -> scan -> bucket-sorted packed scatter ----------------

__global__ void k_hist(const int* __restrict__ dst, int E, int* __restrict__ gh, int NB) {
    __shared__ int sh[NBMAX];
    for (int j = threadIdx.x; j < NB; j += blockDim.x) sh[j] = 0;
    __syncthreads();
    for (int i = blockIdx.x * blockDim.x + threadIdx.x; i < E; i += gridDim.x * blockDim.x)
        atomicAdd(&sh[dst[i] >> SH], 1);
    __syncthreads();
    for (int j = threadIdx.x; j < NB; j += blockDim.x)
        if (sh[j]) atomicAdd(&gh[j], sh[j]);
}

// single block, 1024 threads, chunk=2 -> NB <= 2048. exclusive scan + cursors.
__global__ void k_scan2(const int* __restrict__ gh, int NB, int* __restrict__ boff,
                        int* __restrict__ cur) {
    __shared__ int sh[1024];
    int t = threadIdx.x;
    int i0 = t * 2;
    int a = (i0 < NB) ? gh[i0] : 0;
    int b = (i0 + 1 < NB) ? gh[i0 + 1] : 0;
    sh[t] = a + b;
    __syncthreads();
    for (int off = 1; off < 1024; off <<= 1) {
        int v = (t >= off) ? sh[t - off] : 0;
        __syncthreads();
        sh[t] += v;
        __syncthreads();
    }
    int ex = t ? sh[t - 1] : 0;
    if (i0 < NB) { boff[i0] = ex; cur[i0] = ex; }
    if (i0 + 1 < NB) { boff[i0 + 1] = ex + a; cur[i0 + 1] = ex + a; }
    if (t == 1023) boff[NB] = sh[1023];
}

#define EPT 16
__global__ void k_scatter(const int* __restrict__ src, const int* __restrict__ dst, int E,
                          int NB, int* __restrict__ cur, int* __restrict__ ebuf) {
    __shared__ int lh[NBMAX];
    __shared__ int lb[NBMAX];
    int lo = blockIdx.x * (blockDim.x * EPT);
    for (int j = threadIdx.x; j < NB; j += blockDim.x) lh[j] = 0;
    __syncthreads();
    int s[EPT], d[EPT], rk[EPT];
#pragma unroll
    for (int u = 0; u < EPT; ++u) {
        int e = lo + u * blockDim.x + threadIdx.x;
        if (e < E) {
            s[u] = src[e];
            d[u] = dst[e];
            rk[u] = atomicAdd(&lh[d[u] >> SH], 1);
        }
    }
    __syncthreads();
    for (int j = threadIdx.x; j < NB; j += blockDim.x) {
        int c = lh[j];
        lb[j] = c ? atomicAdd(&cur[j], c) : 0;
    }
    __syncthreads();
#pragma unroll
    for (int u = 0; u < EPT; ++u) {
        int e = lo + u * blockDim.x + threadIdx.x;
        if (e < E) ebuf[lb[d[u] >> SH] + rk[u]] = ((d[u] & (DPB - 1)) << 20) | s[u];
    }
}

__global__ void k_pad_x(const float* __restrict__ x, float* __restrict__ x8, int N) {
    int i = blockIdx.x * blockDim.x + threadIdx.x;
    if (i >= N * 8) return;
    int n = i >> 3, c = i & 7;
    x8[i] = (c < 6) ? x[n * 6 + c] : 0.0f;
}

// ---------------- fused layer kernels ----------------
// 32-channel layers (3 residual blocks + last). LAST: 64 outputs + proj residual.

template <bool LAST>
__global__ __launch_bounds__(256) void k_layer32(
    const float* __restrict__ hin, const int* __restrict__ ebuf_i, const int* __restrict__ boff_i,
    const int* __restrict__ ebuf_t, const int* __restrict__ boff_t,
    const float* __restrict__ Wt, const float* __restrict__ Wi, const float* __restrict__ Wr,
    const float* __restrict__ b, const float* __restrict__ proj, float* __restrict__ out, int N) {
    __shared__ float sm[2 * 65 * 33 + 64 * 33];
    __shared__ int cnt[DPB + 1];
    float* acc_i = sm;                 // [65][33]
    float* acc_t = sm + 65 * 33;       // [65][33]
    float* acc_h = sm + 2 * 65 * 33;   // [64][33] staged self rows
    const int tid = threadIdx.x;
    const int base = blockIdx.x << SH;

    // init: zero accumulators, stage self rows
    for (int i = tid; i < 2 * 65 * 33; i += 256) sm[i] = 0.0f;
    for (int i = tid; i < DPB + 1; i += 256) cnt[i] = 0;
    for (int i = tid; i < DPB * 32; i += 256) {
        int dl = i >> 5, c = i & 31;
        int g = base + dl;
        acc_h[dl * 33 + c] = (g < N) ? hin[(size_t)g * 32 + c] : 0.0f;
    }
    __syncthreads();

    const int lane = tid & 63;
    const int wid = tid >> 6;
    const int r = lane >> 3, q = lane & 7;

    // ---- inter edges (mean; count degrees) ----
    {
        int lo = boff_i[blockIdx.x], hi = boff_i[blockIdx.x + 1];
        for (int e0 = lo + wid * 64; e0 < hi; e0 += 256) {
            int idx = e0 + lane;
            int packed = (idx < hi) ? ebuf_i[idx] : SENT;
            int pks[8];
#pragma unroll
            for (int j = 0; j < 8; ++j) pks[j] = __shfl(packed, j * 8 + r, 64);
            float4 v[8];
#pragma unroll
            for (int j = 0; j < 8; ++j) {
                int s = pks[j] & 0xFFFFF;
                v[j] = *(const float4*)(hin + (size_t)s * 32 + q * 4);
            }
#pragma unroll
            for (int j = 0; j < 8; ++j) {
                int dl = pks[j] >> 20;
                if (q == 0) atomicAdd(&cnt[dl], 1);
                float* a = &acc_i[dl * 33 + q * 4];
                atomicAdd(a + 0, v[j].x);
                atomicAdd(a + 1, v[j].y);
                atomicAdd(a + 2, v[j].z);
                atomicAdd(a + 3, v[j].w);
            }
        }
    }
    // ---- temp edges (sum) ----
    {
        int lo = boff_t[blockIdx.x], hi = boff_t[blockIdx.x + 1];
        for (int e0 = lo + wid * 64; e0 < hi; e0 += 256) {
            int idx = e0 + lane;
            int packed = (idx < hi) ? ebuf_t[idx] : SENT;
            int pks[8];
#pragma unroll
            for (int j = 0; j < 8; ++j) pks[j] = __shfl(packed, j * 8 + r, 64);
            float4 v[8];
#pragma unroll
            for (int j = 0; j < 8; ++j) {
                int s = pks[j] & 0xFFFFF;
                v[j] = *(const float4*)(hin + (size_t)s * 32 + q * 4);
            }
#pragma unroll
            for (int j = 0; j < 8; ++j) {
                int dl = pks[j] >> 20;
                float* a = &acc_t[dl * 33 + q * 4];
                atomicAdd(a + 0, v[j].x);
                atomicAdd(a + 1, v[j].y);
                atomicAdd(a + 2, v[j].z);
                atomicAdd(a + 3, v[j].w);
            }
        }
    }
    __syncthreads();

    // ---- per-node GEMM epilogue ----
    if (!LAST) {
        int c = tid & 31;
        for (int p = 0; p < 8; ++p) {
            int dl = p * 8 + (tid >> 5);
            int g = base + dl;
            if (g >= N) continue;
            float inv = 1.0f / fmaxf((float)cnt[dl], 1.0f);
            const float* Ai = acc_i + dl * 33;
            const float* At = acc_t + dl * 33;
            const float* Ah = acc_h + dl * 33;
            float acc = b[c];
#pragma unroll
            for (int k = 0; k < 32; ++k)
                acc += At[k] * Wt[k * 32 + c] + Ai[k] * inv * Wi[k * 32 + c] +
                       Ah[k] * Wr[k * 32 + c];
            out[(size_t)g * 32 + c] = fmaxf(acc, 0.0f) + Ah[c];
        }
    } else {
        int c = tid & 63;
        for (int p = 0; p < 16; ++p) {
            int dl = p * 4 + (tid >> 6);
            int g = base + dl;
            if (g >= N) continue;
            float inv = 1.0f / fmaxf((float)cnt[dl], 1.0f);
            const float* Ai = acc_i + dl * 33;
            const float* At = acc_t + dl * 33;
            const float* Ah = acc_h + dl * 33;
            float acc = b[c];
            float accp = 0.0f;
#pragma unroll
            for (int k = 0; k < 32; ++k) {
                float ah = Ah[k];
                acc += At[k] * Wt[k * 64 + c] + Ai[k] * inv * Wi[k * 64 + c] +
                       ah * Wr[k * 64 + c];
                accp += ah * proj[k * 64 + c];
            }
            out[(size_t)g * 64 + c] = fmaxf(acc, 0.0f) + accp;
        }
    }
}

// head layer: 8-ch padded input rows (32 B), K=6 -> 32 out.
__global__ __launch_bounds__(256) void k_layer_head(
    const float* __restrict__ x8, const int* __restrict__ ebuf_i, const int* __restrict__ boff_i,
    const int* __restrict__ ebuf_t, const int* __restrict__ boff_t,
    const float* __restrict__ Wt, const float* __restrict__ Wi, const float* __restrict__ Wr,
    const float* __restrict__ b, float* __restrict__ h, int N) {
    __shared__ float sm[2 * 65 * 9 + 64 * 9];
    __shared__ int cnt[DPB + 1];
    float* acc_i = sm;               // [65][9]
    float* acc_t = sm + 65 * 9;      // [65][9]
    float* acc_x = sm + 2 * 65 * 9;  // [64][9]
    const int tid = threadIdx.x;
    const int base = blockIdx.x << SH;

    for (int i = tid; i < 2 * 65 * 9; i += 256) sm[i] = 0.0f;
    for (int i = tid; i < DPB + 1; i += 256) cnt[i] = 0;
    for (int i = tid; i < DPB * 8; i += 256) {
        int dl = i >> 3, c = i & 7;
        int g = base + dl;
        acc_x[dl * 9 + c] = (g < N) ? x8[(size_t)g * 8 + c] : 0.0f;
    }
    __syncthreads();

    const int lane = tid & 63;
    const int wid = tid >> 6;
    const int r = lane >> 1, q = lane & 1;

    {
        int lo = boff_i[blockIdx.x], hi = boff_i[blockIdx.x + 1];
        for (int e0 = lo + wid * 64; e0 < hi; e0 += 256) {
            int idx = e0 + lane;
            int packed = (idx < hi) ? ebuf_i[idx] : SENT;
            int pks[2];
#pragma unroll
            for (int j = 0; j < 2; ++j) pks[j] = __shfl(packed, j * 32 + r, 64);
            float4 v[2];
#pragma unroll
            for (int j = 0; j < 2; ++j) {
                int s = pks[j] & 0xFFFFF;
                v[j] = *(const float4*)(x8 + (size_t)s * 8 + q * 4);
            }
#pragma unroll
            for (int j = 0; j < 2; ++j) {
                int dl = pks[j] >> 20;
                if (q == 0) atomicAdd(&cnt[dl], 1);
                float* a = &acc_i[dl * 9 + q * 4];
                atomicAdd(a + 0, v[j].x);
                atomicAdd(a + 1, v[j].y);
                atomicAdd(a + 2, v[j].z);
                atomicAdd(a + 3, v[j].w);
            }
        }
    }
    {
        int lo = boff_t[blockIdx.x], hi = boff_t[blockIdx.x + 1];
        for (int e0 = lo + wid * 64; e0 < hi; e0 += 256) {
            int idx = e0 + lane;
            int packed = (idx < hi) ? ebuf_t[idx] : SENT;
            int pks[2];
#pragma unroll
            for (int j = 0; j < 2; ++j) pks[j] = __shfl(packed, j * 32 + r, 64);
            float4 v[2];
#pragma unroll
            for (int j = 0; j < 2; ++j) {
                int s = pks[j] & 0xFFFFF;
                v[j] = *(const float4*)(x8 + (size_t)s * 8 + q * 4);
            }
#pragma unroll
            for (int j = 0; j < 2; ++j) {
                int dl = pks[j] >> 20;
                float* a = &acc_t[dl * 9 + q * 4];
                atomicAdd(a + 0, v[j].x);
                atomicAdd(a + 1, v[j].y);
                atomicAdd(a + 2, v[j].z);
                atomicAdd(a + 3, v[j].w);
            }
        }
    }
    __syncthreads();

    int c = tid & 31;
    for (int p = 0; p < 8; ++p) {
        int dl = p * 8 + (tid >> 5);
        int g = base + dl;
        if (g >= N) continue;
        float inv = 1.0f / fmaxf((float)cnt[dl], 1.0f);
        const float* Ai = acc_i + dl * 9;
        const float* At = acc_t + dl * 9;
        const float* Ax = acc_x + dl * 9;
        float acc = b[c];
#pragma unroll
        for (int k = 0; k < 6; ++k)
            acc += At[k] * Wt[k * 32 + c] + Ai[k] * inv * Wi[k * 32 + c] + Ax[k] * Wr[k * 32 + c];
        h[(size_t)g * 32 + c] = fmaxf(acc, 0.0f);
    }
}

// ---------------- launch ----------------

static inline size_t align256(size_t x) { return (x + 255) & ~(size_t)255; }

extern "C" void kernel_launch(void* const* d_in, const int* in_sizes, int n_in,
                              void* d_out, int out_size, void* d_ws, size_t ws_size,
                              hipStream_t stream) {
    const float* x_stroke = (const float*)d_in[0];
    const int* ei_temp = (const int*)d_in[1];
    const int* ei_inter = (const int*)d_in[2];
    const float* head_Wt = (const float*)d_in[3];
    const float* head_Wi = (const float*)d_in[4];
    const float* head_Wr = (const float*)d_in[5];
    const float* head_b = (const float*)d_in[6];
    const float* blk_Wt = (const float*)d_in[7];
    const float* blk_Wi = (const float*)d_in[8];
    const float* blk_Wr = (const float*)d_in[9];
    const float* blk_b = (const float*)d_in[10];
    const float* last_Wt = (const float*)d_in[11];
    const float* last_Wi = (const float*)d_in[12];
    const float* last_Wr = (const float*)d_in[13];
    const float* last_b = (const float*)d_in[14];
    const float* last_proj = (const float*)d_in[15];

    const int N = in_sizes[0] / 6;
    const int Et = in_sizes[1] / 2;
    const int Ei = in_sizes[2] / 2;
    const int NB = ((N - 1) >> SH) + 1;   // assumes <= NBMAX (N <= 131072)

    const int* temp_src = ei_temp;
    const int* temp_dst = ei_temp + Et;
    const int* int_src = ei_inter;
    const int* int_dst = ei_inter + Ei;

    char* p = (char*)d_ws;
    size_t off = 0;
    auto carve = [&](size_t bytes) {
        char* r = p + off;
        off = align256(off + bytes);
        return r;
    };
    int* gh_i = (int*)carve((size_t)NB * 4);
    int* boff_i = (int*)carve((size_t)(NB + 1) * 4);
    int* cur_i = (int*)carve((size_t)NB * 4);
    int* gh_t = (int*)carve((size_t)NB * 4);
    int* boff_t = (int*)carve((size_t)(NB + 1) * 4);
    int* cur_t = (int*)carve((size_t)NB * 4);
    float* x8 = (float*)carve((size_t)N * 8 * 4);
    float* bufA = (float*)carve((size_t)N * 32 * 4);
    float* bufD = (float*)carve((size_t)N * 32 * 4);
    int* ebuf_t = (int*)carve((size_t)Et * 4);
    int* ebuf_i = (int*)carve((size_t)Ei * 4);
    (void)ws_size;

    const int B = 256;
    auto blocks = [&](long long work) { return (int)((work + B - 1) / B); };

    hipMemsetAsync(gh_i, 0, (size_t)NB * 4, stream);
    hipMemsetAsync(gh_t, 0, (size_t)NB * 4, stream);

    k_hist<<<256, B, 0, stream>>>(int_dst, Ei, gh_i, NB);
    k_hist<<<64, B, 0, stream>>>(temp_dst, Et, gh_t, NB);
    k_scan2<<<1, 1024, 0, stream>>>(gh_i, NB, boff_i, cur_i);
    k_scan2<<<1, 1024, 0, stream>>>(gh_t, NB, boff_t, cur_t);
    k_scatter<<<blocks(((long long)Ei + EPT - 1) / EPT), B, 0, stream>>>(int_src, int_dst, Ei, NB,
                                                                         cur_i, ebuf_i);
    k_scatter<<<blocks(((long long)Et + EPT - 1) / EPT), B, 0, stream>>>(temp_src, temp_dst, Et, NB,
                                                                         cur_t, ebuf_t);
    k_pad_x<<<blocks((long long)N * 8), B, 0, stream>>>(x_stroke, x8, N);

    k_layer_head<<<NB, B, 0, stream>>>(x8, ebuf_i, boff_i, ebuf_t, boff_t, head_Wt, head_Wi,
                                       head_Wr, head_b, bufA, N);

    float* hin = bufA;
    float* hout = bufD;
    for (int i = 0; i < 3; ++i) {
        k_layer32<false><<<NB, B, 0, stream>>>(
            hin, ebuf_i, boff_i, ebuf_t, boff_t, blk_Wt + (size_t)i * 32 * 32,
            blk_Wi + (size_t)i * 32 * 32, blk_Wr + (size_t)i * 32 * 32, blk_b + (size_t)i * 32,
            nullptr, hout, N);
        float* t = hin; hin = hout; hout = t;
    }

    k_layer32<true><<<NB, B, 0, stream>>>(hin, ebuf_i, boff_i, ebuf_t, boff_t, last_Wt, last_Wi,
                                          last_Wr, last_b, last_proj, (float*)d_out, N);
}

// Round 6
// 937.281 us; speedup vs baseline: 3.3819x; 3.3819x over previous
//
#include <hip/hip_runtime.h>

// Hetero-GNN: 5 layers of relu(segsum_temp(x)@Wt + segmean_inter(x)@Wi + x@Wr + b)
// (aggregation commuted past the matmuls; aggregate RAW features, fused per-node
// mini-GEMM in the same kernel as the gather). R4 structure (wave per dest,
// padded CSR built via destination binning) + NEW: hidden states are mirrored
// into a bf16 table (64 B rows) used by the neighbor gathers — halves the
// random-gather bytes and fits the 6.4 MB table much closer to per-XCD L2.
// Self/residual path and all weights remain f32.

#define VO 8192   // overflow list capacity (pairs) per relation
#define EPT 16    // edges per thread in k_scatter

__device__ inline void f4add(float4& a, const float4& v) {
    a.x += v.x; a.y += v.y; a.z += v.z; a.w += v.w;
}

__device__ inline float sel4(float a, float b, float c, float d, int k) {
    return (k & 2) ? ((k & 1) ? d : c) : ((k & 1) ? b : a);
}

__device__ inline unsigned short f2bf(float f) {   // RNE f32 -> bf16
    unsigned u = __float_as_uint(f);
    unsigned r = (u + 0x7FFFu + ((u >> 16) & 1u)) >> 16;
    return (unsigned short)r;
}

// ---------------- inter CSR build: hist -> scan -> scatter -> fill ----------------

__global__ void k_hist(const int* __restrict__ dst, int E, int* __restrict__ gh,
                       int NB, int shift) {
    __shared__ int sh[1024];
    for (int j = threadIdx.x; j < NB; j += blockDim.x) sh[j] = 0;
    __syncthreads();
    for (int i = blockIdx.x * blockDim.x + threadIdx.x; i < E; i += gridDim.x * blockDim.x)
        atomicAdd(&sh[dst[i] >> shift], 1);
    __syncthreads();
    for (int j = threadIdx.x; j < NB; j += blockDim.x)
        if (sh[j]) atomicAdd(&gh[j], sh[j]);
}

__global__ void k_scan_b(const int* __restrict__ gh, int NB, int* __restrict__ boff,
                         int* __restrict__ cur) {
    __shared__ int sh[1024];
    int t = threadIdx.x;
    sh[t] = (t < NB) ? gh[t] : 0;
    __syncthreads();
    for (int off = 1; off < 1024; off <<= 1) {
        int v = (t >= off) ? sh[t - off] : 0;
        __syncthreads();
        sh[t] += v;
        __syncthreads();
    }
    if (t < NB) {
        int ex = t ? sh[t - 1] : 0;
        boff[t] = ex;
        cur[t] = ex;
    }
    if (t == 0) boff[NB] = sh[NB - 1];
}

__global__ void k_scatter(const int* __restrict__ src, const int* __restrict__ dst, int E,
                          int shift, int NB, int* __restrict__ cur, int2* __restrict__ ebuf) {
    __shared__ int lh[1024];
    __shared__ int lb[1024];
    int lo = blockIdx.x * (blockDim.x * EPT);
    for (int j = threadIdx.x; j < NB; j += blockDim.x) lh[j] = 0;
    __syncthreads();
    int s[EPT], d[EPT], rk[EPT];
#pragma unroll
    for (int u = 0; u < EPT; ++u) {
        int e = lo + u * blockDim.x + threadIdx.x;
        if (e < E) {
            s[u] = src[e];
            d[u] = dst[e];
            rk[u] = atomicAdd(&lh[d[u] >> shift], 1);
        }
    }
    __syncthreads();
    for (int j = threadIdx.x; j < NB; j += blockDim.x) {
        int c = lh[j];
        lb[j] = c ? atomicAdd(&cur[j], c) : 0;
    }
    __syncthreads();
#pragma unroll
    for (int u = 0; u < EPT; ++u) {
        int e = lo + u * blockDim.x + threadIdx.x;
        if (e < E) ebuf[lb[d[u] >> shift] + rk[u]] = make_int2(s[u], d[u]);
    }
}

__global__ void k_fill3(const int2* __restrict__ ebuf, const int* __restrict__ boff, int NB,
                        int* __restrict__ cnt, int* __restrict__ csr, int Ci,
                        int* __restrict__ ovf, int* __restrict__ ovf_n) {
    int b = blockIdx.x;
    if (b >= NB) return;
    int lo = boff[b], hi = boff[b + 1];
    for (int e = lo + threadIdx.x; e < hi; e += blockDim.x) {
        int2 sd = ebuf[e];
        int slot = atomicAdd(&cnt[sd.y], 1);
        if (slot < Ci) {
            csr[(size_t)sd.y * Ci + slot] = sd.x;
        } else {
            int p = atomicAdd(ovf_n, 1);
            if (p < VO) { ovf[2 * p] = sd.y; ovf[2 * p + 1] = sd.x; }
        }
    }
}

__global__ void k_fill2(const int* __restrict__ src, const int* __restrict__ dst, int E,
                        int* __restrict__ cnt, int* __restrict__ csr, int C,
                        int* __restrict__ ovf, int* __restrict__ ovf_n) {
    int i = blockIdx.x * blockDim.x + threadIdx.x;
    if (i >= E) return;
    int s = src[i];
    int d = dst[i];
    int slot = atomicAdd(&cnt[d], 1);
    if (slot < C) {
        csr[(size_t)d * C + slot] = s;
    } else {
        int p = atomicAdd(ovf_n, 1);
        if (p < VO) { ovf[2 * p] = d; ovf[2 * p + 1] = s; }
    }
}

__global__ void k_pad_x(const float* __restrict__ x, float* __restrict__ x8, int N) {
    int i = blockIdx.x * blockDim.x + threadIdx.x;
    if (i >= N * 8) return;
    int n = i >> 3, c = i & 7;
    x8[i] = (c < 6) ? x[n * 6 + c] : 0.0f;
}

// ---------------- f32 gather (head layer, 8ch padded rows) ----------------

template <int CHV, int U, bool MASK>
__device__ inline void g_grp(const float* __restrict__ x, int sv, int it0, int nb,
                             int q, int r, float4& acc) {
    const int R = 64 / CHV;
    int s[U];
    float4 v[U];
#pragma unroll
    for (int u = 0; u < U; ++u) s[u] = __shfl(sv, (it0 + u) * R + r, 64);
#pragma unroll
    for (int u = 0; u < U; ++u) v[u] = *(const float4*)(x + (size_t)s[u] * (CHV * 4) + q * 4);
#pragma unroll
    for (int u = 0; u < U; ++u) {
        if (MASK) {
            float m = ((it0 + u) * R + r < nb) ? 1.0f : 0.0f;
            acc.x = fmaf(m, v[u].x, acc.x);
            acc.y = fmaf(m, v[u].y, acc.y);
            acc.z = fmaf(m, v[u].z, acc.z);
            acc.w = fmaf(m, v[u].w, acc.w);
        } else {
            f4add(acc, v[u]);
        }
    }
}

template <int CHV, int U>
__device__ inline float4 gather_one(const float* __restrict__ x, const int* __restrict__ csr,
                                    size_t rowbase, int cnt_c, int lane, int q, int r) {
    const int R = 64 / CHV;
    float4 acc = make_float4(0.f, 0.f, 0.f, 0.f);
    for (int base = 0; base < cnt_c; base += 64) {
        int nb = min(64, cnt_c - base);
        int sv = (lane < nb) ? csr[rowbase + base + lane] : 0;
        int it = 0;
        while ((it + U) * R <= nb) {
            g_grp<CHV, U, false>(x, sv, it, nb, q, r, acc);
            it += U;
        }
        if (it * R < nb) g_grp<CHV, U, true>(x, sv, it, nb, q, r, acc);
    }
    return acc;
}

template <int CHV>
__device__ inline void ovf_add(const float* __restrict__ x, const int* __restrict__ ovf, int n,
                               int g, int q, int r, float4& acc) {
    for (int j = 0; j < n; ++j) {
        int d = ovf[2 * j];
        if (d == g) {
            int s = ovf[2 * j + 1];
            if (r == 0) f4add(acc, *(const float4*)(x + (size_t)s * (CHV * 4) + q * 4));
        }
    }
}

template <int CHV>
__device__ inline void reduce4(float4& a) {
#pragma unroll
    for (int st = CHV; st < 64; st <<= 1) {
        a.x += __shfl_xor(a.x, st, 64);
        a.y += __shfl_xor(a.y, st, 64);
        a.z += __shfl_xor(a.z, st, 64);
        a.w += __shfl_xor(a.w, st, 64);
    }
}

// ---------------- bf16 gather (hidden layers, 64 B rows = 16 dwords) ----------------
// lane: q = lane&3 (16 B quarter of row), r = lane>>2 (16 rows per group-iter).
// acc[8] = channels q*8 .. q*8+7 (dword d -> acc[2d]=lo ch, acc[2d+1]=hi ch).

template <int U, bool MASK>
__device__ inline void g_grp_bf(const unsigned* __restrict__ hb, int sv, int it0, int nb,
                                int q, int r, float acc[8]) {
    int s[U];
    uint4 v[U];
#pragma unroll
    for (int u = 0; u < U; ++u) s[u] = __shfl(sv, (it0 + u) * 16 + r, 64);
#pragma unroll
    for (int u = 0; u < U; ++u) v[u] = *(const uint4*)(hb + (size_t)s[u] * 16 + q * 4);
#pragma unroll
    for (int u = 0; u < U; ++u) {
        float m = ((it0 + u) * 16 + r < nb) ? 1.0f : 0.0f;
        unsigned w[4] = {v[u].x, v[u].y, v[u].z, v[u].w};
#pragma unroll
        for (int d = 0; d < 4; ++d) {
            float lo = __uint_as_float(w[d] << 16);
            float hi = __uint_as_float(w[d] & 0xFFFF0000u);
            if (MASK) {
                acc[2 * d] = fmaf(m, lo, acc[2 * d]);
                acc[2 * d + 1] = fmaf(m, hi, acc[2 * d + 1]);
            } else {
                acc[2 * d] += lo;
                acc[2 * d + 1] += hi;
            }
        }
    }
}

template <int U>
__device__ inline void gather_bf(const unsigned* __restrict__ hb, const int* __restrict__ csr,
                                 size_t rowbase, int cnt_c, int lane, int q, int r, float acc[8]) {
#pragma unroll
    for (int j = 0; j < 8; ++j) acc[j] = 0.0f;
    for (int base = 0; base < cnt_c; base += 64) {
        int nb = min(64, cnt_c - base);
        int sv = (lane < nb) ? csr[rowbase + base + lane] : 0;
        int it = 0;
        while ((it + U) * 16 <= nb) {
            g_grp_bf<U, false>(hb, sv, it, nb, q, r, acc);
            it += U;
        }
        if (it * 16 < nb) g_grp_bf<U, true>(hb, sv, it, nb, q, r, acc);
    }
}

__device__ inline void ovf_add_bf(const unsigned* __restrict__ hb, const int* __restrict__ ovf,
                                  int n, int g, int q, int r, float acc[8]) {
    for (int j = 0; j < n; ++j) {
        int d = ovf[2 * j];
        if (d == g && r == 0) {
            int s = ovf[2 * j + 1];
            uint4 v = *(const uint4*)(hb + (size_t)s * 16 + q * 4);
            unsigned w[4] = {v.x, v.y, v.z, v.w};
#pragma unroll
            for (int dd = 0; dd < 4; ++dd) {
                acc[2 * dd] += __uint_as_float(w[dd] << 16);
                acc[2 * dd + 1] += __uint_as_float(w[dd] & 0xFFFF0000u);
            }
        }
    }
}

__device__ inline void reduce8(float a[8]) {
#pragma unroll
    for (int st = 4; st < 64; st <<= 1)
#pragma unroll
        for (int j = 0; j < 8; ++j) a[j] += __shfl_xor(a[j], st, 64);
}

// channel pick: acc[j] (j = hc&7) from lane sq = hc>>3 (lanes 0..3 hold q=0..3)
__device__ inline float pick8(const float a[8], int sq, int vidx) {
    float t0 = __shfl(a[0], sq, 64), t1 = __shfl(a[1], sq, 64);
    float t2 = __shfl(a[2], sq, 64), t3 = __shfl(a[3], sq, 64);
    float t4 = __shfl(a[4], sq, 64), t5 = __shfl(a[5], sq, 64);
    float t6 = __shfl(a[6], sq, 64), t7 = __shfl(a[7], sq, 64);
    float lo = sel4(t0, t1, t2, t3, vidx & 3);
    float hi = sel4(t4, t5, t6, t7, vidx & 3);
    return (vidx & 4) ? hi : lo;
}

// ---------------- fused gather + per-node GEMM layers ----------------

__global__ __launch_bounds__(256) void k_layer_head(
    const float* __restrict__ x8, const int* __restrict__ csr_i, const int* __restrict__ cnt_i,
    int Ci, const int* __restrict__ csr_t, const int* __restrict__ cnt_t, int Ct,
    const int* __restrict__ ovf_i, const int* __restrict__ ovf_t, const int* __restrict__ ovfn,
    const float* __restrict__ Wt, const float* __restrict__ Wi, const float* __restrict__ Wr,
    const float* __restrict__ b, float* __restrict__ h, unsigned short* __restrict__ hb_out,
    int N) {
    int tid = blockIdx.x * blockDim.x + threadIdx.x;
    int g = tid >> 6;
    if (g >= N) return;
    int lane = threadIdx.x & 63;
    int q = lane & 1, r = lane >> 1;
    int cif = cnt_i[g], ci = min(cif, Ci);
    int ctf = cnt_t[g], ct = min(ctf, Ct);
    float4 ai = gather_one<2, 2>(x8, csr_i, (size_t)g * Ci, ci, lane, q, r);
    float4 at = gather_one<2, 1>(x8, csr_t, (size_t)g * Ct, ct, lane, q, r);
    if (cif > Ci) ovf_add<2>(x8, ovf_i, min(ovfn[0], VO), g, q, r, ai);
    if (ctf > Ct) ovf_add<2>(x8, ovf_t, min(ovfn[1], VO), g, q, r, at);
    reduce4<2>(ai);
    reduce4<2>(at);
    float inv = 1.0f / (float)max(cif, 1);
    ai.x *= inv; ai.y *= inv; ai.z *= inv; ai.w *= inv;
    float a_i[6] = {__shfl(ai.x, 0, 64), __shfl(ai.y, 0, 64), __shfl(ai.z, 0, 64),
                    __shfl(ai.w, 0, 64), __shfl(ai.x, 1, 64), __shfl(ai.y, 1, 64)};
    float a_t[6] = {__shfl(at.x, 0, 64), __shfl(at.y, 0, 64), __shfl(at.z, 0, 64),
                    __shfl(at.w, 0, 64), __shfl(at.x, 1, 64), __shfl(at.y, 1, 64)};
    float vx = (lane < 6) ? x8[(size_t)g * 8 + lane] : 0.0f;
    int hc = lane & 31;
    float acc = b[hc];
#pragma unroll
    for (int k = 0; k < 6; ++k) {
        float ax = __shfl(vx, k, 64);
        acc += a_t[k] * Wt[k * 32 + hc] + a_i[k] * Wi[k * 32 + hc] + ax * Wr[k * 32 + hc];
    }
    if (lane < 32) {
        float o = fmaxf(acc, 0.0f);
        h[(size_t)g * 32 + hc] = o;
        hb_out[(size_t)g * 32 + hc] = f2bf(o);
    }
}

__global__ __launch_bounds__(256) void k_layer_blk(
    const float* __restrict__ hin, const unsigned* __restrict__ hb,
    const int* __restrict__ csr_i, const int* __restrict__ cnt_i, int Ci,
    const int* __restrict__ csr_t, const int* __restrict__ cnt_t, int Ct,
    const int* __restrict__ ovf_i, const int* __restrict__ ovf_t, const int* __restrict__ ovfn,
    const float* __restrict__ Wt, const float* __restrict__ Wi, const float* __restrict__ Wr,
    const float* __restrict__ b, float* __restrict__ hout, unsigned short* __restrict__ hb_out,
    int N) {
    int tid = blockIdx.x * blockDim.x + threadIdx.x;
    int g = tid >> 6;
    if (g >= N) return;
    int lane = threadIdx.x & 63;
    int q = lane & 3, r = lane >> 2;
    int cif = cnt_i[g], ci = min(cif, Ci);
    int ctf = cnt_t[g], ct = min(ctf, Ct);
    float ai[8], at[8];
    gather_bf<2>(hb, csr_i, (size_t)g * Ci, ci, lane, q, r, ai);
    gather_bf<1>(hb, csr_t, (size_t)g * Ct, ct, lane, q, r, at);
    if (cif > Ci) ovf_add_bf(hb, ovf_i, min(ovfn[0], VO), g, q, r, ai);
    if (ctf > Ct) ovf_add_bf(hb, ovf_t, min(ovfn[1], VO), g, q, r, at);
    reduce8(ai);
    reduce8(at);
    float inv = 1.0f / (float)max(cif, 1);
    int hc = lane & 31, sq = hc >> 3, vidx = hc & 7;
    float vi = pick8(ai, sq, vidx) * inv;
    float vt = pick8(at, sq, vidx);
    float vh = hin[(size_t)g * 32 + hc];
    float acc = 0.0f;
    int kbase = (lane >> 5) << 4;
#pragma unroll
    for (int it = 0; it < 16; ++it) {
        int k = kbase + it;
        float bi = __shfl(vi, k, 64), bt = __shfl(vt, k, 64), bh = __shfl(vh, k, 64);
        acc += bt * Wt[k * 32 + hc] + bi * Wi[k * 32 + hc] + bh * Wr[k * 32 + hc];
    }
    acc += __shfl_xor(acc, 32, 64);
    if (lane < 32) {
        float o = fmaxf(acc + b[hc], 0.0f) + vh;
        hout[(size_t)g * 32 + hc] = o;
        hb_out[(size_t)g * 32 + hc] = f2bf(o);
    }
}

__global__ __launch_bounds__(256) void k_layer_last(
    const float* __restrict__ hin, const unsigned* __restrict__ hb,
    const int* __restrict__ csr_i, const int* __restrict__ cnt_i, int Ci,
    const int* __restrict__ csr_t, const int* __restrict__ cnt_t, int Ct,
    const int* __restrict__ ovf_i, const int* __restrict__ ovf_t, const int* __restrict__ ovfn,
    const float* __restrict__ Wt, const float* __restrict__ Wi, const float* __restrict__ Wr,
    const float* __restrict__ b, const float* __restrict__ proj, float* __restrict__ out, int N) {
    int tid = blockIdx.x * blockDim.x + threadIdx.x;
    int g = tid >> 6;
    if (g >= N) return;
    int lane = threadIdx.x & 63;
    int q = lane & 3, r = lane >> 2;
    int cif = cnt_i[g], ci = min(cif, Ci);
    int ctf = cnt_t[g], ct = min(ctf, Ct);
    float ai[8], at[8];
    gather_bf<2>(hb, csr_i, (size_t)g * Ci, ci, lane, q, r, ai);
    gather_bf<1>(hb, csr_t, (size_t)g * Ct, ct, lane, q, r, at);
    if (cif > Ci) ovf_add_bf(hb, ovf_i, min(ovfn[0], VO), g, q, r, ai);
    if (ctf > Ct) ovf_add_bf(hb, ovf_t, min(ovfn[1], VO), g, q, r, at);
    reduce8(ai);
    reduce8(at);
    float inv = 1.0f / (float)max(cif, 1);
    int hc = lane & 31, sq = hc >> 3, vidx = hc & 7;
    float vi = pick8(ai, sq, vidx) * inv;
    float vt = pick8(at, sq, vidx);
    float vh = hin[(size_t)g * 32 + hc];
    int ch = lane;
    float acc = b[ch];
    float accp = 0.0f;
    for (int k = 0; k < 32; ++k) {
        float bi = __shfl(vi, k, 64), bt = __shfl(vt, k, 64), bh = __shfl(vh, k, 64);
        acc += bt * Wt[k * 64 + ch] + bi * Wi[k * 64 + ch] + bh * Wr[k * 64 + ch];
        accp += bh * proj[k * 64 + ch];
    }
    out[(size_t)g * 64 + ch] = fmaxf(acc, 0.0f) + accp;
}

// ---------------- launch ----------------

static inline size_t align256(size_t x) { return (x + 255) & ~(size_t)255; }

extern "C" void kernel_launch(void* const* d_in, const int* in_sizes, int n_in,
                              void* d_out, int out_size, void* d_ws, size_t ws_size,
                              hipStream_t stream) {
    const float* x_stroke = (const float*)d_in[0];
    const int* ei_temp = (const int*)d_in[1];
    const int* ei_inter = (const int*)d_in[2];
    const float* head_Wt = (const float*)d_in[3];
    const float* head_Wi = (const float*)d_in[4];
    const float* head_Wr = (const float*)d_in[5];
    const float* head_b = (const float*)d_in[6];
    const float* blk_Wt = (const float*)d_in[7];
    const float* blk_Wi = (const float*)d_in[8];
    const float* blk_Wr = (const float*)d_in[9];
    const float* blk_b = (const float*)d_in[10];
    const float* last_Wt = (const float*)d_in[11];
    const float* last_Wi = (const float*)d_in[12];
    const float* last_Wr = (const float*)d_in[13];
    const float* last_b = (const float*)d_in[14];
    const float* last_proj = (const float*)d_in[15];

    const int N = in_sizes[0] / 6;
    const int Et = in_sizes[1] / 2;
    const int Ei = in_sizes[2] / 2;

    const int* temp_src = ei_temp;
    const int* temp_dst = ei_temp + Et;
    const int* int_src = ei_inter;
    const int* int_dst = ei_inter + Ei;

    int shift = 7;
    while ((((N - 1) >> shift) + 1) > 1024) ++shift;
    const int NB = ((N - 1) >> shift) + 1;

    char* p = (char*)d_ws;
    size_t off = 0;
    auto carve = [&](size_t bytes) {
        char* r = p + off;
        off = align256(off + bytes);
        return r;
    };
    int* cnt_i = (int*)carve((size_t)N * 4);
    int* cnt_t = (int*)carve((size_t)N * 4);
    int* ovfn = (int*)carve(2 * 4);
    int* ovf_i = (int*)carve((size_t)VO * 8);
    int* ovf_t = (int*)carve((size_t)VO * 8);
    int* gh = (int*)carve((size_t)NB * 4);
    int* boff = (int*)carve((size_t)(NB + 1) * 4);
    int* cur = (int*)carve((size_t)NB * 4);
    float* x8 = (float*)carve((size_t)N * 8 * 4);
    float* bufA = (float*)carve((size_t)N * 32 * 4);
    float* bufD = (float*)carve((size_t)N * 32 * 4);
    unsigned short* hbA = (unsigned short*)carve((size_t)N * 32 * 2);
    unsigned short* hbD = (unsigned short*)carve((size_t)N * 32 * 2);
    int2* ebuf = (int2*)carve((size_t)Ei * 8);
    int Ct = 16, Ci = 64;
    {
        size_t avail = (ws_size > off) ? (ws_size - off) : 0;
        size_t cap = avail / ((size_t)N * 4);
        if ((size_t)(Ct + Ci) > cap) {
            Ct = 8;
            Ci = (cap > (size_t)Ct) ? (int)(cap - Ct) : 4;
            if (Ci > 64) Ci = 64;
        }
    }
    int* csr_t = (int*)carve((size_t)N * Ct * 4);
    int* csr_i = (int*)carve((size_t)N * Ci * 4);

    const int B = 256;
    auto blocks = [&](long long work) { return (int)((work + B - 1) / B); };

    hipMemsetAsync(cnt_i, 0, (size_t)N * 4, stream);
    hipMemsetAsync(cnt_t, 0, (size_t)N * 4, stream);
    hipMemsetAsync(ovfn, 0, 2 * 4, stream);
    hipMemsetAsync(gh, 0, (size_t)NB * 4, stream);

    k_hist<<<256, B, 0, stream>>>(int_dst, Ei, gh, NB, shift);
    k_scan_b<<<1, 1024, 0, stream>>>(gh, NB, boff, cur);
    k_scatter<<<blocks(((long long)Ei + EPT - 1) / EPT), B, 0, stream>>>(int_src, int_dst, Ei,
                                                                         shift, NB, cur, ebuf);
    k_fill3<<<NB, B, 0, stream>>>(ebuf, boff, NB, cnt_i, csr_i, Ci, ovf_i, &ovfn[0]);
    k_fill2<<<blocks(Et), B, 0, stream>>>(temp_src, temp_dst, Et, cnt_t, csr_t, Ct, ovf_t, &ovfn[1]);
    k_pad_x<<<blocks((long long)N * 8), B, 0, stream>>>(x_stroke, x8, N);

    k_layer_head<<<blocks((long long)N * 64), B, 0, stream>>>(
        x8, csr_i, cnt_i, Ci, csr_t, cnt_t, Ct, ovf_i, ovf_t, ovfn, head_Wt, head_Wi, head_Wr,
        head_b, bufA, hbA, N);

    float* hin = bufA;
    float* hout = bufD;
    unsigned short* hb_in = hbA;
    unsigned short* hb_out = hbD;
    for (int i = 0; i < 3; ++i) {
        k_layer_blk<<<blocks((long long)N * 64), B, 0, stream>>>(
            hin, (const unsigned*)hb_in, csr_i, cnt_i, Ci, csr_t, cnt_t, Ct, ovf_i, ovf_t, ovfn,
            blk_Wt + (size_t)i * 32 * 32, blk_Wi + (size_t)i * 32 * 32,
            blk_Wr + (size_t)i * 32 * 32, blk_b + (size_t)i * 32, hout, hb_out, N);
        float* t = hin; hin = hout; hout = t;
        unsigned short* tb = hb_in; hb_in = hb_out; hb_out = tb;
    }

    k_layer_last<<<blocks((long long)N * 64), B, 0, stream>>>(
        hin, (const unsigned*)hb_in, csr_i, cnt_i, Ci, csr_t, cnt_t, Ct, ovf_i, ovf_t, ovfn,
        last_Wt, last_Wi, last_Wr, last_b, last_proj, (float*)d_out, N);
}

// Round 7
// 768.271 us; speedup vs baseline: 4.1259x; 1.2200x over previous
//
#include <hip/hip_runtime.h>

// Hetero-GNN: 5 layers of relu(segsum_temp(x)@Wt + segmean_inter(x)@Wi + x@Wr + b)
// (aggregation commuted past the matmuls; aggregate RAW features, fused per-node
// mini-GEMM in the same kernel as the gather). R4 structure (wave per dest,
// padded CSR built via destination binning) + NEW: the gather's row loads are
// issued via inline asm (4x global_load_dwordx4 + ONE s_waitcnt vmcnt(0)) so the
// compiler cannot serialize them — R4/R6 evidence: source-level unrolling was
// re-serialized (VGPR 24, one load in flight, latency-bound at 42% VALU).

#define VO 8192   // overflow list capacity (pairs) per relation
#define EPT 16    // edges per thread in k_scatter

typedef float vf4 __attribute__((ext_vector_type(4)));

__device__ inline void f4add(float4& a, const float4& v) {
    a.x += v.x; a.y += v.y; a.z += v.z; a.w += v.w;
}

__device__ inline float sel4(float a, float b, float c, float d, int k) {
    return (k & 2) ? ((k & 1) ? d : c) : ((k & 1) ? b : a);
}

// ---------------- inter CSR build: hist -> scan -> scatter -> fill ----------------

__global__ void k_hist(const int* __restrict__ dst, int E, int* __restrict__ gh,
                       int NB, int shift) {
    __shared__ int sh[1024];
    for (int j = threadIdx.x; j < NB; j += blockDim.x) sh[j] = 0;
    __syncthreads();
    for (int i = blockIdx.x * blockDim.x + threadIdx.x; i < E; i += gridDim.x * blockDim.x)
        atomicAdd(&sh[dst[i] >> shift], 1);
    __syncthreads();
    for (int j = threadIdx.x; j < NB; j += blockDim.x)
        if (sh[j]) atomicAdd(&gh[j], sh[j]);
}

__global__ void k_scan_b(const int* __restrict__ gh, int NB, int* __restrict__ boff,
                         int* __restrict__ cur) {
    __shared__ int sh[1024];
    int t = threadIdx.x;
    sh[t] = (t < NB) ? gh[t] : 0;
    __syncthreads();
    for (int off = 1; off < 1024; off <<= 1) {
        int v = (t >= off) ? sh[t - off] : 0;
        __syncthreads();
        sh[t] += v;
        __syncthreads();
    }
    if (t < NB) {
        int ex = t ? sh[t - 1] : 0;
        boff[t] = ex;
        cur[t] = ex;
    }
    if (t == 0) boff[NB] = sh[NB - 1];
}

__global__ void k_scatter(const int* __restrict__ src, const int* __restrict__ dst, int E,
                          int shift, int NB, int* __restrict__ cur, int2* __restrict__ ebuf) {
    __shared__ int lh[1024];
    __shared__ int lb[1024];
    int lo = blockIdx.x * (blockDim.x * EPT);
    for (int j = threadIdx.x; j < NB; j += blockDim.x) lh[j] = 0;
    __syncthreads();
    int s[EPT], d[EPT], rk[EPT];
#pragma unroll
    for (int u = 0; u < EPT; ++u) {
        int e = lo + u * blockDim.x + threadIdx.x;
        if (e < E) {
            s[u] = src[e];
            d[u] = dst[e];
            rk[u] = atomicAdd(&lh[d[u] >> shift], 1);
        }
    }
    __syncthreads();
    for (int j = threadIdx.x; j < NB; j += blockDim.x) {
        int c = lh[j];
        lb[j] = c ? atomicAdd(&cur[j], c) : 0;
    }
    __syncthreads();
#pragma unroll
    for (int u = 0; u < EPT; ++u) {
        int e = lo + u * blockDim.x + threadIdx.x;
        if (e < E) ebuf[lb[d[u] >> shift] + rk[u]] = make_int2(s[u], d[u]);
    }
}

__global__ void k_fill3(const int2* __restrict__ ebuf, const int* __restrict__ boff, int NB,
                        int* __restrict__ cnt, int* __restrict__ csr, int Ci,
                        int* __restrict__ ovf, int* __restrict__ ovf_n) {
    int b = blockIdx.x;
    if (b >= NB) return;
    int lo = boff[b], hi = boff[b + 1];
    for (int e = lo + threadIdx.x; e < hi; e += blockDim.x) {
        int2 sd = ebuf[e];
        int slot = atomicAdd(&cnt[sd.y], 1);
        if (slot < Ci) {
            csr[(size_t)sd.y * Ci + slot] = sd.x;
        } else {
            int p = atomicAdd(ovf_n, 1);
            if (p < VO) { ovf[2 * p] = sd.y; ovf[2 * p + 1] = sd.x; }
        }
    }
}

__global__ void k_fill2(const int* __restrict__ src, const int* __restrict__ dst, int E,
                        int* __restrict__ cnt, int* __restrict__ csr, int C,
                        int* __restrict__ ovf, int* __restrict__ ovf_n) {
    int i = blockIdx.x * blockDim.x + threadIdx.x;
    if (i >= E) return;
    int s = src[i];
    int d = dst[i];
    int slot = atomicAdd(&cnt[d], 1);
    if (slot < C) {
        csr[(size_t)d * C + slot] = s;
    } else {
        int p = atomicAdd(ovf_n, 1);
        if (p < VO) { ovf[2 * p] = d; ovf[2 * p + 1] = s; }
    }
}

__global__ void k_pad_x(const float* __restrict__ x, float* __restrict__ x8, int N) {
    int i = blockIdx.x * blockDim.x + threadIdx.x;
    if (i >= N * 8) return;
    int n = i >> 3, c = i & 7;
    x8[i] = (c < 6) ? x[n * 6 + c] : 0.0f;
}

// ---------------- f32 gathers ----------------
// head (CHV=2, plain C) unchanged from R4.

template <int CHV, int U, bool MASK>
__device__ inline void g_grp(const float* __restrict__ x, int sv, int it0, int nb,
                             int q, int r, float4& acc) {
    const int R = 64 / CHV;
    int s[U];
    float4 v[U];
#pragma unroll
    for (int u = 0; u < U; ++u) s[u] = __shfl(sv, (it0 + u) * R + r, 64);
#pragma unroll
    for (int u = 0; u < U; ++u) v[u] = *(const float4*)(x + (size_t)s[u] * (CHV * 4) + q * 4);
#pragma unroll
    for (int u = 0; u < U; ++u) {
        if (MASK) {
            float m = ((it0 + u) * R + r < nb) ? 1.0f : 0.0f;
            acc.x = fmaf(m, v[u].x, acc.x);
            acc.y = fmaf(m, v[u].y, acc.y);
            acc.z = fmaf(m, v[u].z, acc.z);
            acc.w = fmaf(m, v[u].w, acc.w);
        } else {
            f4add(acc, v[u]);
        }
    }
}

template <int CHV, int U>
__device__ inline float4 gather_one(const float* __restrict__ x, const int* __restrict__ csr,
                                    size_t rowbase, int cnt_c, int lane, int q, int r) {
    const int R = 64 / CHV;
    float4 acc = make_float4(0.f, 0.f, 0.f, 0.f);
    for (int base = 0; base < cnt_c; base += 64) {
        int nb = min(64, cnt_c - base);
        int sv = (lane < nb) ? csr[rowbase + base + lane] : 0;
        int it = 0;
        while ((it + U) * R <= nb) {
            g_grp<CHV, U, false>(x, sv, it, nb, q, r, acc);
            it += U;
        }
        if (it * R < nb) g_grp<CHV, U, true>(x, sv, it, nb, q, r, acc);
    }
    return acc;
}

// ---- 32-ch asm gathers: 4 loads in flight, ONE vmcnt(0) ----
// lane: q = lane&7 (16 B eighth of 128 B row), r = lane>>3 (8 rows per group).

__device__ inline float4 gather_asm4(const float* __restrict__ x, const int* __restrict__ csr,
                                     size_t rowbase, int cnt_c, int lane, int q, int r) {
    float4 acc = make_float4(0.f, 0.f, 0.f, 0.f);
    for (int base = 0; base < cnt_c; base += 64) {
        int nb = min(64, cnt_c - base);
        int sv = (lane < nb) ? csr[rowbase + base + lane] : 0;
        for (int it = 0; it * 8 < nb; it += 4) {
            int s0 = __shfl(sv, (it + 0) * 8 + r, 64);
            int s1 = __shfl(sv, (it + 1) * 8 + r, 64);
            int s2 = __shfl(sv, (it + 2) * 8 + r, 64);
            int s3 = __shfl(sv, (it + 3) * 8 + r, 64);
            const float* a0 = x + (size_t)s0 * 32 + q * 4;
            const float* a1 = x + (size_t)s1 * 32 + q * 4;
            const float* a2 = x + (size_t)s2 * 32 + q * 4;
            const float* a3 = x + (size_t)s3 * 32 + q * 4;
            vf4 v0, v1, v2, v3;
            asm volatile(
                "global_load_dwordx4 %0, %4, off\n\t"
                "global_load_dwordx4 %1, %5, off\n\t"
                "global_load_dwordx4 %2, %6, off\n\t"
                "global_load_dwordx4 %3, %7, off\n\t"
                "s_waitcnt vmcnt(0)"
                : "=&v"(v0), "=&v"(v1), "=&v"(v2), "=&v"(v3)
                : "v"(a0), "v"(a1), "v"(a2), "v"(a3)
                : "memory");
            if ((it + 4) * 8 <= nb) {   // wave-uniform: full group of 32 rows
                acc.x += v0.x + v1.x + v2.x + v3.x;
                acc.y += v0.y + v1.y + v2.y + v3.y;
                acc.z += v0.z + v1.z + v2.z + v3.z;
                acc.w += v0.w + v1.w + v2.w + v3.w;
            } else {
                float m0 = ((it + 0) * 8 + r < nb) ? 1.0f : 0.0f;
                float m1 = ((it + 1) * 8 + r < nb) ? 1.0f : 0.0f;
                float m2 = ((it + 2) * 8 + r < nb) ? 1.0f : 0.0f;
                float m3 = ((it + 3) * 8 + r < nb) ? 1.0f : 0.0f;
                acc.x = fmaf(m0, v0.x, fmaf(m1, v1.x, fmaf(m2, v2.x, fmaf(m3, v3.x, acc.x))));
                acc.y = fmaf(m0, v0.y, fmaf(m1, v1.y, fmaf(m2, v2.y, fmaf(m3, v3.y, acc.y))));
                acc.z = fmaf(m0, v0.z, fmaf(m1, v1.z, fmaf(m2, v2.z, fmaf(m3, v3.z, acc.z))));
                acc.w = fmaf(m0, v0.w, fmaf(m1, v1.w, fmaf(m2, v2.w, fmaf(m3, v3.w, acc.w))));
            }
        }
    }
    return acc;
}

// single-load variant for the temp relation (deg ~1)
__device__ inline float4 gather_asm1(const float* __restrict__ x, const int* __restrict__ csr,
                                     size_t rowbase, int cnt_c, int lane, int q, int r) {
    float4 acc = make_float4(0.f, 0.f, 0.f, 0.f);
    for (int base = 0; base < cnt_c; base += 64) {
        int nb = min(64, cnt_c - base);
        int sv = (lane < nb) ? csr[rowbase + base + lane] : 0;
        for (int it = 0; it * 8 < nb; ++it) {
            int s0 = __shfl(sv, it * 8 + r, 64);
            const float* a0 = x + (size_t)s0 * 32 + q * 4;
            vf4 v0;
            asm volatile(
                "global_load_dwordx4 %0, %1, off\n\t"
                "s_waitcnt vmcnt(0)"
                : "=&v"(v0)
                : "v"(a0)
                : "memory");
            float m0 = (it * 8 + r < nb) ? 1.0f : 0.0f;
            acc.x = fmaf(m0, v0.x, acc.x);
            acc.y = fmaf(m0, v0.y, acc.y);
            acc.z = fmaf(m0, v0.z, acc.z);
            acc.w = fmaf(m0, v0.w, acc.w);
        }
    }
    return acc;
}

template <int CHV>
__device__ inline void ovf_add(const float* __restrict__ x, const int* __restrict__ ovf, int n,
                               int g, int q, int r, float4& acc) {
    for (int j = 0; j < n; ++j) {
        int d = ovf[2 * j];
        if (d == g) {
            int s = ovf[2 * j + 1];
            if (r == 0) f4add(acc, *(const float4*)(x + (size_t)s * (CHV * 4) + q * 4));
        }
    }
}

template <int CHV>
__device__ inline void reduce4(float4& a) {
#pragma unroll
    for (int st = CHV; st < 64; st <<= 1) {
        a.x += __shfl_xor(a.x, st, 64);
        a.y += __shfl_xor(a.y, st, 64);
        a.z += __shfl_xor(a.z, st, 64);
        a.w += __shfl_xor(a.w, st, 64);
    }
}

// ---------------- fused gather + per-node GEMM layers ----------------

__global__ __launch_bounds__(256) void k_layer_head(
    const float* __restrict__ x8, const int* __restrict__ csr_i, const int* __restrict__ cnt_i,
    int Ci, const int* __restrict__ csr_t, const int* __restrict__ cnt_t, int Ct,
    const int* __restrict__ ovf_i, const int* __restrict__ ovf_t, const int* __restrict__ ovfn,
    const float* __restrict__ Wt, const float* __restrict__ Wi, const float* __restrict__ Wr,
    const float* __restrict__ b, float* __restrict__ h, int N) {
    int tid = blockIdx.x * blockDim.x + threadIdx.x;
    int g = tid >> 6;
    if (g >= N) return;
    int lane = threadIdx.x & 63;
    int q = lane & 1, r = lane >> 1;
    int cif = cnt_i[g], ci = min(cif, Ci);
    int ctf = cnt_t[g], ct = min(ctf, Ct);
    float4 ai = gather_one<2, 2>(x8, csr_i, (size_t)g * Ci, ci, lane, q, r);
    float4 at = gather_one<2, 1>(x8, csr_t, (size_t)g * Ct, ct, lane, q, r);
    if (cif > Ci) ovf_add<2>(x8, ovf_i, min(ovfn[0], VO), g, q, r, ai);
    if (ctf > Ct) ovf_add<2>(x8, ovf_t, min(ovfn[1], VO), g, q, r, at);
    reduce4<2>(ai);
    reduce4<2>(at);
    float inv = 1.0f / (float)max(cif, 1);
    ai.x *= inv; ai.y *= inv; ai.z *= inv; ai.w *= inv;
    float a_i[6] = {__shfl(ai.x, 0, 64), __shfl(ai.y, 0, 64), __shfl(ai.z, 0, 64),
                    __shfl(ai.w, 0, 64), __shfl(ai.x, 1, 64), __shfl(ai.y, 1, 64)};
    float a_t[6] = {__shfl(at.x, 0, 64), __shfl(at.y, 0, 64), __shfl(at.z, 0, 64),
                    __shfl(at.w, 0, 64), __shfl(at.x, 1, 64), __shfl(at.y, 1, 64)};
    float vx = (lane < 6) ? x8[(size_t)g * 8 + lane] : 0.0f;
    int hc = lane & 31;
    float acc = b[hc];
#pragma unroll
    for (int k = 0; k < 6; ++k) {
        float ax = __shfl(vx, k, 64);
        acc += a_t[k] * Wt[k * 32 + hc] + a_i[k] * Wi[k * 32 + hc] + ax * Wr[k * 32 + hc];
    }
    if (lane < 32) h[(size_t)g * 32 + hc] = fmaxf(acc, 0.0f);
}

__global__ __launch_bounds__(256) void k_layer_blk(
    const float* __restrict__ hin, const int* __restrict__ csr_i, const int* __restrict__ cnt_i,
    int Ci, const int* __restrict__ csr_t, const int* __restrict__ cnt_t, int Ct,
    const int* __restrict__ ovf_i, const int* __restrict__ ovf_t, const int* __restrict__ ovfn,
    const float* __restrict__ Wt, const float* __restrict__ Wi, const float* __restrict__ Wr,
    const float* __restrict__ b, float* __restrict__ hout, int N) {
    int tid = blockIdx.x * blockDim.x + threadIdx.x;
    int g = tid >> 6;
    if (g >= N) return;
    int lane = threadIdx.x & 63;
    int q = lane & 7, r = lane >> 3;
    int cif = cnt_i[g], ci = min(cif, Ci);
    int ctf = cnt_t[g], ct = min(ctf, Ct);
    float4 ai = gather_asm4(hin, csr_i, (size_t)g * Ci, ci, lane, q, r);
    float4 at = gather_asm1(hin, csr_t, (size_t)g * Ct, ct, lane, q, r);
    if (cif > Ci) ovf_add<8>(hin, ovf_i, min(ovfn[0], VO), g, q, r, ai);
    if (ctf > Ct) ovf_add<8>(hin, ovf_t, min(ovfn[1], VO), g, q, r, at);
    reduce4<8>(ai);
    reduce4<8>(at);
    float inv = 1.0f / (float)max(cif, 1);
    int hc = lane & 31, sq = hc >> 2, sc = hc & 3;
    float vi = sel4(__shfl(ai.x, sq, 64), __shfl(ai.y, sq, 64), __shfl(ai.z, sq, 64),
                    __shfl(ai.w, sq, 64), sc) * inv;
    float vt = sel4(__shfl(at.x, sq, 64), __shfl(at.y, sq, 64), __shfl(at.z, sq, 64),
                    __shfl(at.w, sq, 64), sc);
    float vh = hin[(size_t)g * 32 + hc];
    float acc = 0.0f;
    int kbase = (lane >> 5) << 4;
#pragma unroll
    for (int it = 0; it < 16; ++it) {
        int k = kbase + it;
        float bi = __shfl(vi, k, 64), bt = __shfl(vt, k, 64), bh = __shfl(vh, k, 64);
        acc += bt * Wt[k * 32 + hc] + bi * Wi[k * 32 + hc] + bh * Wr[k * 32 + hc];
    }
    acc += __shfl_xor(acc, 32, 64);
    if (lane < 32) hout[(size_t)g * 32 + hc] = fmaxf(acc + b[hc], 0.0f) + vh;
}

__global__ __launch_bounds__(256) void k_layer_last(
    const float* __restrict__ hin, const int* __restrict__ csr_i, const int* __restrict__ cnt_i,
    int Ci, const int* __restrict__ csr_t, const int* __restrict__ cnt_t, int Ct,
    const int* __restrict__ ovf_i, const int* __restrict__ ovf_t, const int* __restrict__ ovfn,
    const float* __restrict__ Wt, const float* __restrict__ Wi, const float* __restrict__ Wr,
    const float* __restrict__ b, const float* __restrict__ proj, float* __restrict__ out, int N) {
    int tid = blockIdx.x * blockDim.x + threadIdx.x;
    int g = tid >> 6;
    if (g >= N) return;
    int lane = threadIdx.x & 63;
    int q = lane & 7, r = lane >> 3;
    int cif = cnt_i[g], ci = min(cif, Ci);
    int ctf = cnt_t[g], ct = min(ctf, Ct);
    float4 ai = gather_asm4(hin, csr_i, (size_t)g * Ci, ci, lane, q, r);
    float4 at = gather_asm1(hin, csr_t, (size_t)g * Ct, ct, lane, q, r);
    if (cif > Ci) ovf_add<8>(hin, ovf_i, min(ovfn[0], VO), g, q, r, ai);
    if (ctf > Ct) ovf_add<8>(hin, ovf_t, min(ovfn[1], VO), g, q, r, at);
    reduce4<8>(ai);
    reduce4<8>(at);
    float inv = 1.0f / (float)max(cif, 1);
    int hc = lane & 31, sq = hc >> 2, sc = hc & 3;
    float vi = sel4(__shfl(ai.x, sq, 64), __shfl(ai.y, sq, 64), __shfl(ai.z, sq, 64),
                    __shfl(ai.w, sq, 64), sc) * inv;
    float vt = sel4(__shfl(at.x, sq, 64), __shfl(at.y, sq, 64), __shfl(at.z, sq, 64),
                    __shfl(at.w, sq, 64), sc);
    float vh = hin[(size_t)g * 32 + hc];
    int ch = lane;
    float acc = b[ch];
    float accp = 0.0f;
    for (int k = 0; k < 32; ++k) {
        float bi = __shfl(vi, k, 64), bt = __shfl(vt, k, 64), bh = __shfl(vh, k, 64);
        acc += bt * Wt[k * 64 + ch] + bi * Wi[k * 64 + ch] + bh * Wr[k * 64 + ch];
        accp += bh * proj[k * 64 + ch];
    }
    out[(size_t)g * 64 + ch] = fmaxf(acc, 0.0f) + accp;
}

// ---------------- launch ----------------

static inline size_t align256(size_t x) { return (x + 255) & ~(size_t)255; }

extern "C" void kernel_launch(void* const* d_in, const int* in_sizes, int n_in,
                              void* d_out, int out_size, void* d_ws, size_t ws_size,
                              hipStream_t stream) {
    const float* x_stroke = (const float*)d_in[0];
    const int* ei_temp = (const int*)d_in[1];
    const int* ei_inter = (const int*)d_in[2];
    const float* head_Wt = (const float*)d_in[3];
    const float* head_Wi = (const float*)d_in[4];
    const float* head_Wr = (const float*)d_in[5];
    const float* head_b = (const float*)d_in[6];
    const float* blk_Wt = (const float*)d_in[7];
    const float* blk_Wi = (const float*)d_in[8];
    const float* blk_Wr = (const float*)d_in[9];
    const float* blk_b = (const float*)d_in[10];
    const float* last_Wt = (const float*)d_in[11];
    const float* last_Wi = (const float*)d_in[12];
    const float* last_Wr = (const float*)d_in[13];
    const float* last_b = (const float*)d_in[14];
    const float* last_proj = (const float*)d_in[15];

    const int N = in_sizes[0] / 6;
    const int Et = in_sizes[1] / 2;
    const int Ei = in_sizes[2] / 2;

    const int* temp_src = ei_temp;
    const int* temp_dst = ei_temp + Et;
    const int* int_src = ei_inter;
    const int* int_dst = ei_inter + Ei;

    int shift = 7;
    while ((((N - 1) >> shift) + 1) > 1024) ++shift;
    const int NB = ((N - 1) >> shift) + 1;

    char* p = (char*)d_ws;
    size_t off = 0;
    auto carve = [&](size_t bytes) {
        char* r = p + off;
        off = align256(off + bytes);
        return r;
    };
    int* cnt_i = (int*)carve((size_t)N * 4);
    int* cnt_t = (int*)carve((size_t)N * 4);
    int* ovfn = (int*)carve(2 * 4);
    int* ovf_i = (int*)carve((size_t)VO * 8);
    int* ovf_t = (int*)carve((size_t)VO * 8);
    int* gh = (int*)carve((size_t)NB * 4);
    int* boff = (int*)carve((size_t)(NB + 1) * 4);
    int* cur = (int*)carve((size_t)NB * 4);
    float* x8 = (float*)carve((size_t)N * 8 * 4);
    float* bufA = (float*)carve((size_t)N * 32 * 4);
    float* bufD = (float*)carve((size_t)N * 32 * 4);
    int2* ebuf = (int2*)carve((size_t)Ei * 8);
    int Ct = 16, Ci = 64;
    {
        size_t avail = (ws_size > off) ? (ws_size - off) : 0;
        size_t cap = avail / ((size_t)N * 4);
        if ((size_t)(Ct + Ci) > cap) {
            Ct = 8;
            Ci = (cap > (size_t)Ct) ? (int)(cap - Ct) : 4;
            if (Ci > 64) Ci = 64;
        }
    }
    int* csr_t = (int*)carve((size_t)N * Ct * 4);
    int* csr_i = (int*)carve((size_t)N * Ci * 4);

    const int B = 256;
    auto blocks = [&](long long work) { return (int)((work + B - 1) / B); };

    hipMemsetAsync(cnt_i, 0, (size_t)N * 4, stream);
    hipMemsetAsync(cnt_t, 0, (size_t)N * 4, stream);
    hipMemsetAsync(ovfn, 0, 2 * 4, stream);
    hipMemsetAsync(gh, 0, (size_t)NB * 4, stream);

    k_hist<<<256, B, 0, stream>>>(int_dst, Ei, gh, NB, shift);
    k_scan_b<<<1, 1024, 0, stream>>>(gh, NB, boff, cur);
    k_scatter<<<blocks(((long long)Ei + EPT - 1) / EPT), B, 0, stream>>>(int_src, int_dst, Ei,
                                                                         shift, NB, cur, ebuf);
    k_fill3<<<NB, B, 0, stream>>>(ebuf, boff, NB, cnt_i, csr_i, Ci, ovf_i, &ovfn[0]);
    k_fill2<<<blocks(Et), B, 0, stream>>>(temp_src, temp_dst, Et, cnt_t, csr_t, Ct, ovf_t, &ovfn[1]);
    k_pad_x<<<blocks((long long)N * 8), B, 0, stream>>>(x_stroke, x8, N);

    k_layer_head<<<blocks((long long)N * 64), B, 0, stream>>>(
        x8, csr_i, cnt_i, Ci, csr_t, cnt_t, Ct, ovf_i, ovf_t, ovfn, head_Wt, head_Wi, head_Wr,
        head_b, bufA, N);

    float* hin = bufA;
    float* hout = bufD;
    for (int i = 0; i < 3; ++i) {
        k_layer_blk<<<blocks((long long)N * 64), B, 0, stream>>>(
            hin, csr_i, cnt_i, Ci, csr_t, cnt_t, Ct, ovf_i, ovf_t, ovfn,
            blk_Wt + (size_t)i * 32 * 32, blk_Wi + (size_t)i * 32 * 32,
            blk_Wr + (size_t)i * 32 * 32, blk_b + (size_t)i * 32, hout, N);
        float* t = hin; hin = hout; hout = t;
    }

    k_layer_last<<<blocks((long long)N * 64), B, 0, stream>>>(
        hin, csr_i, cnt_i, Ci, csr_t, cnt_t, Ct, ovf_i, ovf_t, ovfn, last_Wt, last_Wi, last_Wr,
        last_b, last_proj, (float*)d_out, N);
}

// Round 8
// 680.555 us; speedup vs baseline: 4.6577x; 1.1289x over previous
//
#include <hip/hip_runtime.h>

// Hetero-GNN: 5 layers of relu(segsum_temp(x)@Wt + segmean_inter(x)@Wi + x@Wr + b)
// (aggregation commuted past the matmuls).
//
// R8: hidden layers SPLIT into (a) k_gather32 — wave-per-destination asm gather
// (4 row loads in flight, one vmcnt) writing agg[n][64] = [aggi*inv | aggt]; and
// (b) k_gemm_* — thread-per-node mini-GEMM with acc[] in VGPRs and wave-uniform
// weight rows (scalarized loads), 32-64 fma per weight fetch. R3-R7 evidence:
// the fused epilogue reloaded 128 weight values per node (VGPR=28, serial L1
// chains) and dominated the 168 µs/layer; the gather's own floors are far lower.

#define VO 8192   // overflow list capacity (pairs) per relation
#define EPT 16    // edges per thread in k_scatter

typedef float vf4 __attribute__((ext_vector_type(4)));

__device__ inline void f4add(float4& a, const float4& v) {
    a.x += v.x; a.y += v.y; a.z += v.z; a.w += v.w;
}

// ---------------- inter CSR build: hist -> scan -> scatter -> fill ----------------

__global__ void k_hist(const int* __restrict__ dst, int E, int* __restrict__ gh,
                       int NB, int shift) {
    __shared__ int sh[1024];
    for (int j = threadIdx.x; j < NB; j += blockDim.x) sh[j] = 0;
    __syncthreads();
    for (int i = blockIdx.x * blockDim.x + threadIdx.x; i < E; i += gridDim.x * blockDim.x)
        atomicAdd(&sh[dst[i] >> shift], 1);
    __syncthreads();
    for (int j = threadIdx.x; j < NB; j += blockDim.x)
        if (sh[j]) atomicAdd(&gh[j], sh[j]);
}

__global__ void k_scan_b(const int* __restrict__ gh, int NB, int* __restrict__ boff,
                         int* __restrict__ cur) {
    __shared__ int sh[1024];
    int t = threadIdx.x;
    sh[t] = (t < NB) ? gh[t] : 0;
    __syncthreads();
    for (int off = 1; off < 1024; off <<= 1) {
        int v = (t >= off) ? sh[t - off] : 0;
        __syncthreads();
        sh[t] += v;
        __syncthreads();
    }
    if (t < NB) {
        int ex = t ? sh[t - 1] : 0;
        boff[t] = ex;
        cur[t] = ex;
    }
    if (t == 0) boff[NB] = sh[NB - 1];
}

__global__ void k_scatter(const int* __restrict__ src, const int* __restrict__ dst, int E,
                          int shift, int NB, int* __restrict__ cur, int2* __restrict__ ebuf) {
    __shared__ int lh[1024];
    __shared__ int lb[1024];
    int lo = blockIdx.x * (blockDim.x * EPT);
    for (int j = threadIdx.x; j < NB; j += blockDim.x) lh[j] = 0;
    __syncthreads();
    int s[EPT], d[EPT], rk[EPT];
#pragma unroll
    for (int u = 0; u < EPT; ++u) {
        int e = lo + u * blockDim.x + threadIdx.x;
        if (e < E) {
            s[u] = src[e];
            d[u] = dst[e];
            rk[u] = atomicAdd(&lh[d[u] >> shift], 1);
        }
    }
    __syncthreads();
    for (int j = threadIdx.x; j < NB; j += blockDim.x) {
        int c = lh[j];
        lb[j] = c ? atomicAdd(&cur[j], c) : 0;
    }
    __syncthreads();
#pragma unroll
    for (int u = 0; u < EPT; ++u) {
        int e = lo + u * blockDim.x + threadIdx.x;
        if (e < E) ebuf[lb[d[u] >> shift] + rk[u]] = make_int2(s[u], d[u]);
    }
}

__global__ void k_fill3(const int2* __restrict__ ebuf, const int* __restrict__ boff, int NB,
                        int* __restrict__ cnt, int* __restrict__ csr, int Ci,
                        int* __restrict__ ovf, int* __restrict__ ovf_n) {
    int b = blockIdx.x;
    if (b >= NB) return;
    int lo = boff[b], hi = boff[b + 1];
    for (int e = lo + threadIdx.x; e < hi; e += blockDim.x) {
        int2 sd = ebuf[e];
        int slot = atomicAdd(&cnt[sd.y], 1);
        if (slot < Ci) {
            csr[(size_t)sd.y * Ci + slot] = sd.x;
        } else {
            int p = atomicAdd(ovf_n, 1);
            if (p < VO) { ovf[2 * p] = sd.y; ovf[2 * p + 1] = sd.x; }
        }
    }
}

__global__ void k_fill2(const int* __restrict__ src, const int* __restrict__ dst, int E,
                        int* __restrict__ cnt, int* __restrict__ csr, int C,
                        int* __restrict__ ovf, int* __restrict__ ovf_n) {
    int i = blockIdx.x * blockDim.x + threadIdx.x;
    if (i >= E) return;
    int s = src[i];
    int d = dst[i];
    int slot = atomicAdd(&cnt[d], 1);
    if (slot < C) {
        csr[(size_t)d * C + slot] = s;
    } else {
        int p = atomicAdd(ovf_n, 1);
        if (p < VO) { ovf[2 * p] = d; ovf[2 * p + 1] = s; }
    }
}

__global__ void k_pad_x(const float* __restrict__ x, float* __restrict__ x8, int N) {
    int i = blockIdx.x * blockDim.x + threadIdx.x;
    if (i >= N * 8) return;
    int n = i >> 3, c = i & 7;
    x8[i] = (c < 6) ? x[n * 6 + c] : 0.0f;
}

// ---------------- f32 gathers ----------------

template <int CHV, int U, bool MASK>
__device__ inline void g_grp(const float* __restrict__ x, int sv, int it0, int nb,
                             int q, int r, float4& acc) {
    const int R = 64 / CHV;
    int s[U];
    float4 v[U];
#pragma unroll
    for (int u = 0; u < U; ++u) s[u] = __shfl(sv, (it0 + u) * R + r, 64);
#pragma unroll
    for (int u = 0; u < U; ++u) v[u] = *(const float4*)(x + (size_t)s[u] * (CHV * 4) + q * 4);
#pragma unroll
    for (int u = 0; u < U; ++u) {
        if (MASK) {
            float m = ((it0 + u) * R + r < nb) ? 1.0f : 0.0f;
            acc.x = fmaf(m, v[u].x, acc.x);
            acc.y = fmaf(m, v[u].y, acc.y);
            acc.z = fmaf(m, v[u].z, acc.z);
            acc.w = fmaf(m, v[u].w, acc.w);
        } else {
            f4add(acc, v[u]);
        }
    }
}

template <int CHV, int U>
__device__ inline float4 gather_one(const float* __restrict__ x, const int* __restrict__ csr,
                                    size_t rowbase, int cnt_c, int lane, int q, int r) {
    const int R = 64 / CHV;
    float4 acc = make_float4(0.f, 0.f, 0.f, 0.f);
    for (int base = 0; base < cnt_c; base += 64) {
        int nb = min(64, cnt_c - base);
        int sv = (lane < nb) ? csr[rowbase + base + lane] : 0;
        int it = 0;
        while ((it + U) * R <= nb) {
            g_grp<CHV, U, false>(x, sv, it, nb, q, r, acc);
            it += U;
        }
        if (it * R < nb) g_grp<CHV, U, true>(x, sv, it, nb, q, r, acc);
    }
    return acc;
}

// ---- 32-ch asm gathers: 4 loads in flight, ONE vmcnt(0) ----
// lane: q = lane&7 (16 B eighth of 128 B row), r = lane>>3 (8 rows per group).

__device__ inline float4 gather_asm4(const float* __restrict__ x, const int* __restrict__ csr,
                                     size_t rowbase, int cnt_c, int lane, int q, int r) {
    float4 acc = make_float4(0.f, 0.f, 0.f, 0.f);
    for (int base = 0; base < cnt_c; base += 64) {
        int nb = min(64, cnt_c - base);
        int sv = (lane < nb) ? csr[rowbase + base + lane] : 0;
        for (int it = 0; it * 8 < nb; it += 4) {
            int s0 = __shfl(sv, (it + 0) * 8 + r, 64);
            int s1 = __shfl(sv, (it + 1) * 8 + r, 64);
            int s2 = __shfl(sv, (it + 2) * 8 + r, 64);
            int s3 = __shfl(sv, (it + 3) * 8 + r, 64);
            const float* a0 = x + (size_t)s0 * 32 + q * 4;
            const float* a1 = x + (size_t)s1 * 32 + q * 4;
            const float* a2 = x + (size_t)s2 * 32 + q * 4;
            const float* a3 = x + (size_t)s3 * 32 + q * 4;
            vf4 v0, v1, v2, v3;
            asm volatile(
                "global_load_dwordx4 %0, %4, off\n\t"
                "global_load_dwordx4 %1, %5, off\n\t"
                "global_load_dwordx4 %2, %6, off\n\t"
                "global_load_dwordx4 %3, %7, off\n\t"
                "s_waitcnt vmcnt(0)"
                : "=&v"(v0), "=&v"(v1), "=&v"(v2), "=&v"(v3)
                : "v"(a0), "v"(a1), "v"(a2), "v"(a3)
                : "memory");
            if ((it + 4) * 8 <= nb) {   // wave-uniform: full group of 32 rows
                acc.x += v0.x + v1.x + v2.x + v3.x;
                acc.y += v0.y + v1.y + v2.y + v3.y;
                acc.z += v0.z + v1.z + v2.z + v3.z;
                acc.w += v0.w + v1.w + v2.w + v3.w;
            } else {
                float m0 = ((it + 0) * 8 + r < nb) ? 1.0f : 0.0f;
                float m1 = ((it + 1) * 8 + r < nb) ? 1.0f : 0.0f;
                float m2 = ((it + 2) * 8 + r < nb) ? 1.0f : 0.0f;
                float m3 = ((it + 3) * 8 + r < nb) ? 1.0f : 0.0f;
                acc.x = fmaf(m0, v0.x, fmaf(m1, v1.x, fmaf(m2, v2.x, fmaf(m3, v3.x, acc.x))));
                acc.y = fmaf(m0, v0.y, fmaf(m1, v1.y, fmaf(m2, v2.y, fmaf(m3, v3.y, acc.y))));
                acc.z = fmaf(m0, v0.z, fmaf(m1, v1.z, fmaf(m2, v2.z, fmaf(m3, v3.z, acc.z))));
                acc.w = fmaf(m0, v0.w, fmaf(m1, v1.w, fmaf(m2, v2.w, fmaf(m3, v3.w, acc.w))));
            }
        }
    }
    return acc;
}

__device__ inline float4 gather_asm1(const float* __restrict__ x, const int* __restrict__ csr,
                                     size_t rowbase, int cnt_c, int lane, int q, int r) {
    float4 acc = make_float4(0.f, 0.f, 0.f, 0.f);
    for (int base = 0; base < cnt_c; base += 64) {
        int nb = min(64, cnt_c - base);
        int sv = (lane < nb) ? csr[rowbase + base + lane] : 0;
        for (int it = 0; it * 8 < nb; ++it) {
            int s0 = __shfl(sv, it * 8 + r, 64);
            const float* a0 = x + (size_t)s0 * 32 + q * 4;
            vf4 v0;
            asm volatile(
                "global_load_dwordx4 %0, %1, off\n\t"
                "s_waitcnt vmcnt(0)"
                : "=&v"(v0)
                : "v"(a0)
                : "memory");
            float m0 = (it * 8 + r < nb) ? 1.0f : 0.0f;
            acc.x = fmaf(m0, v0.x, acc.x);
            acc.y = fmaf(m0, v0.y, acc.y);
            acc.z = fmaf(m0, v0.z, acc.z);
            acc.w = fmaf(m0, v0.w, acc.w);
        }
    }
    return acc;
}

template <int CHV>
__device__ inline void ovf_add(const float* __restrict__ x, const int* __restrict__ ovf, int n,
                               int g, int q, int r, float4& acc) {
    for (int j = 0; j < n; ++j) {
        int d = ovf[2 * j];
        if (d == g) {
            int s = ovf[2 * j + 1];
            if (r == 0) f4add(acc, *(const float4*)(x + (size_t)s * (CHV * 4) + q * 4));
        }
    }
}

template <int CHV>
__device__ inline void reduce4(float4& a) {
#pragma unroll
    for (int st = CHV; st < 64; st <<= 1) {
        a.x += __shfl_xor(a.x, st, 64);
        a.y += __shfl_xor(a.y, st, 64);
        a.z += __shfl_xor(a.z, st, 64);
        a.w += __shfl_xor(a.w, st, 64);
    }
}

// ---------------- head layer (fused, unchanged) ----------------

__global__ __launch_bounds__(256) void k_layer_head(
    const float* __restrict__ x8, const int* __restrict__ csr_i, const int* __restrict__ cnt_i,
    int Ci, const int* __restrict__ csr_t, const int* __restrict__ cnt_t, int Ct,
    const int* __restrict__ ovf_i, const int* __restrict__ ovf_t, const int* __restrict__ ovfn,
    const float* __restrict__ Wt, const float* __restrict__ Wi, const float* __restrict__ Wr,
    const float* __restrict__ b, float* __restrict__ h, int N) {
    int tid = blockIdx.x * blockDim.x + threadIdx.x;
    int g = tid >> 6;
    if (g >= N) return;
    int lane = threadIdx.x & 63;
    int q = lane & 1, r = lane >> 1;
    int cif = cnt_i[g], ci = min(cif, Ci);
    int ctf = cnt_t[g], ct = min(ctf, Ct);
    float4 ai = gather_one<2, 2>(x8, csr_i, (size_t)g * Ci, ci, lane, q, r);
    float4 at = gather_one<2, 1>(x8, csr_t, (size_t)g * Ct, ct, lane, q, r);
    if (cif > Ci) ovf_add<2>(x8, ovf_i, min(ovfn[0], VO), g, q, r, ai);
    if (ctf > Ct) ovf_add<2>(x8, ovf_t, min(ovfn[1], VO), g, q, r, at);
    reduce4<2>(ai);
    reduce4<2>(at);
    float inv = 1.0f / (float)max(cif, 1);
    ai.x *= inv; ai.y *= inv; ai.z *= inv; ai.w *= inv;
    float a_i[6] = {__shfl(ai.x, 0, 64), __shfl(ai.y, 0, 64), __shfl(ai.z, 0, 64),
                    __shfl(ai.w, 0, 64), __shfl(ai.x, 1, 64), __shfl(ai.y, 1, 64)};
    float a_t[6] = {__shfl(at.x, 0, 64), __shfl(at.y, 0, 64), __shfl(at.z, 0, 64),
                    __shfl(at.w, 0, 64), __shfl(at.x, 1, 64), __shfl(at.y, 1, 64)};
    float vx = (lane < 6) ? x8[(size_t)g * 8 + lane] : 0.0f;
    int hc = lane & 31;
    float acc = b[hc];
#pragma unroll
    for (int k = 0; k < 6; ++k) {
        float ax = __shfl(vx, k, 64);
        acc += a_t[k] * Wt[k * 32 + hc] + a_i[k] * Wi[k * 32 + hc] + ax * Wr[k * 32 + hc];
    }
    if (lane < 32) h[(size_t)g * 32 + hc] = fmaxf(acc, 0.0f);
}

// ---------------- hidden-layer gather: writes agg[n][64] = [aggi*inv | aggt] ----------------

__global__ __launch_bounds__(256) void k_gather32(
    const float* __restrict__ hin, const int* __restrict__ csr_i, const int* __restrict__ cnt_i,
    int Ci, const int* __restrict__ csr_t, const int* __restrict__ cnt_t, int Ct,
    const int* __restrict__ ovf_i, const int* __restrict__ ovf_t, const int* __restrict__ ovfn,
    float* __restrict__ agg, int N) {
    int tid = blockIdx.x * blockDim.x + threadIdx.x;
    int g = tid >> 6;
    if (g >= N) return;
    int lane = threadIdx.x & 63;
    int q = lane & 7, r = lane >> 3;
    int cif = cnt_i[g], ci = min(cif, Ci);
    int ctf = cnt_t[g], ct = min(ctf, Ct);
    float4 ai = gather_asm4(hin, csr_i, (size_t)g * Ci, ci, lane, q, r);
    float4 at = gather_asm1(hin, csr_t, (size_t)g * Ct, ct, lane, q, r);
    if (cif > Ci) ovf_add<8>(hin, ovf_i, min(ovfn[0], VO), g, q, r, ai);
    if (ctf > Ct) ovf_add<8>(hin, ovf_t, min(ovfn[1], VO), g, q, r, at);
    reduce4<8>(ai);
    reduce4<8>(at);
    float inv = 1.0f / (float)max(cif, 1);
    if (r == 0) {
        float4 o = make_float4(ai.x * inv, ai.y * inv, ai.z * inv, ai.w * inv);
        *(float4*)(agg + (size_t)g * 64 + q * 4) = o;
    } else if (r == 1) {
        *(float4*)(agg + (size_t)g * 64 + 32 + q * 4) = at;
    }
}

// ---------------- per-node GEMM kernels (thread = node, weights wave-uniform) ----------------

template <int OC>
__device__ inline void gemm_seg(const float* __restrict__ seg, const float* __restrict__ W,
                                float* acc) {
#pragma unroll 2
    for (int k4 = 0; k4 < 8; ++k4) {
        float4 a = ((const float4*)seg)[k4];
        float av[4] = {a.x, a.y, a.z, a.w};
#pragma unroll
        for (int i = 0; i < 4; ++i) {
            const float* Wk = W + (k4 * 4 + i) * OC;
#pragma unroll
            for (int c = 0; c < OC; ++c) acc[c] = fmaf(av[i], Wk[c], acc[c]);
        }
    }
}

__global__ __launch_bounds__(256) void k_gemm_blk(
    const float* __restrict__ agg, const float* __restrict__ hin,
    const float* __restrict__ Wt, const float* __restrict__ Wi, const float* __restrict__ Wr,
    const float* __restrict__ b, float* __restrict__ hout, int N) {
    int n = blockIdx.x * blockDim.x + threadIdx.x;
    if (n >= N) return;
    float acc[32];
#pragma unroll
    for (int c = 0; c < 32; ++c) acc[c] = b[c];
    const float* Ai = agg + (size_t)n * 64;        // mean already applied
    const float* At = agg + (size_t)n * 64 + 32;
    const float* H = hin + (size_t)n * 32;
    gemm_seg<32>(At, Wt, acc);
    gemm_seg<32>(Ai, Wi, acc);
    gemm_seg<32>(H, Wr, acc);
    float* O = hout + (size_t)n * 32;
#pragma unroll
    for (int c4 = 0; c4 < 8; ++c4) {
        float4 hv = ((const float4*)H)[c4];
        float4 o = make_float4(fmaxf(acc[c4 * 4 + 0], 0.f) + hv.x,
                               fmaxf(acc[c4 * 4 + 1], 0.f) + hv.y,
                               fmaxf(acc[c4 * 4 + 2], 0.f) + hv.z,
                               fmaxf(acc[c4 * 4 + 3], 0.f) + hv.w);
        ((float4*)O)[c4] = o;
    }
}

__global__ __launch_bounds__(256) void k_gemm_last(
    const float* __restrict__ agg, const float* __restrict__ hin,
    const float* __restrict__ Wt, const float* __restrict__ Wi, const float* __restrict__ Wr,
    const float* __restrict__ b, const float* __restrict__ proj, float* __restrict__ out, int N) {
    int n = blockIdx.x * blockDim.x + threadIdx.x;
    if (n >= N) return;
    float acc[64];
#pragma unroll
    for (int c = 0; c < 64; ++c) acc[c] = b[c];
    const float* Ai = agg + (size_t)n * 64;
    const float* At = agg + (size_t)n * 64 + 32;
    const float* H = hin + (size_t)n * 32;
    gemm_seg<64>(At, Wt, acc);
    gemm_seg<64>(Ai, Wi, acc);
    gemm_seg<64>(H, Wr, acc);
#pragma unroll
    for (int c = 0; c < 64; ++c) acc[c] = fmaxf(acc[c], 0.f);
    gemm_seg<64>(H, proj, acc);   // + hin @ proj
    float* O = out + (size_t)n * 64;
#pragma unroll
    for (int c4 = 0; c4 < 16; ++c4)
        ((float4*)O)[c4] = make_float4(acc[c4 * 4 + 0], acc[c4 * 4 + 1],
                                       acc[c4 * 4 + 2], acc[c4 * 4 + 3]);
}

// ---------------- launch ----------------

static inline size_t align256(size_t x) { return (x + 255) & ~(size_t)255; }

extern "C" void kernel_launch(void* const* d_in, const int* in_sizes, int n_in,
                              void* d_out, int out_size, void* d_ws, size_t ws_size,
                              hipStream_t stream) {
    const float* x_stroke = (const float*)d_in[0];
    const int* ei_temp = (const int*)d_in[1];
    const int* ei_inter = (const int*)d_in[2];
    const float* head_Wt = (const float*)d_in[3];
    const float* head_Wi = (const float*)d_in[4];
    const float* head_Wr = (const float*)d_in[5];
    const float* head_b = (const float*)d_in[6];
    const float* blk_Wt = (const float*)d_in[7];
    const float* blk_Wi = (const float*)d_in[8];
    const float* blk_Wr = (const float*)d_in[9];
    const float* blk_b = (const float*)d_in[10];
    const float* last_Wt = (const float*)d_in[11];
    const float* last_Wi = (const float*)d_in[12];
    const float* last_Wr = (const float*)d_in[13];
    const float* last_b = (const float*)d_in[14];
    const float* last_proj = (const float*)d_in[15];

    const int N = in_sizes[0] / 6;
    const int Et = in_sizes[1] / 2;
    const int Ei = in_sizes[2] / 2;

    const int* temp_src = ei_temp;
    const int* temp_dst = ei_temp + Et;
    const int* int_src = ei_inter;
    const int* int_dst = ei_inter + Ei;

    int shift = 7;
    while ((((N - 1) >> shift) + 1) > 1024) ++shift;
    const int NB = ((N - 1) >> shift) + 1;

    char* p = (char*)d_ws;
    size_t off = 0;
    auto carve = [&](size_t bytes) {
        char* r = p + off;
        off = align256(off + bytes);
        return r;
    };
    int* cnt_i = (int*)carve((size_t)N * 4);
    int* cnt_t = (int*)carve((size_t)N * 4);
    int* ovfn = (int*)carve(2 * 4);
    int* ovf_i = (int*)carve((size_t)VO * 8);
    int* ovf_t = (int*)carve((size_t)VO * 8);
    int* gh = (int*)carve((size_t)NB * 4);
    int* boff = (int*)carve((size_t)(NB + 1) * 4);
    int* cur = (int*)carve((size_t)NB * 4);
    float* x8 = (float*)carve((size_t)N * 8 * 4);
    float* bufA = (float*)carve((size_t)N * 32 * 4);
    float* bufD = (float*)carve((size_t)N * 32 * 4);
    float* agg = (float*)carve((size_t)N * 64 * 4);
    int2* ebuf = (int2*)carve((size_t)Ei * 8);
    int Ct = 16, Ci = 64;
    {
        size_t avail = (ws_size > off) ? (ws_size - off) : 0;
        size_t cap = avail / ((size_t)N * 4);
        if ((size_t)(Ct + Ci) > cap) {
            Ct = 8;
            Ci = (cap > (size_t)Ct) ? (int)(cap - Ct) : 4;
            if (Ci > 64) Ci = 64;
        }
    }
    int* csr_t = (int*)carve((size_t)N * Ct * 4);
    int* csr_i = (int*)carve((size_t)N * Ci * 4);

    const int B = 256;
    auto blocks = [&](long long work) { return (int)((work + B - 1) / B); };

    hipMemsetAsync(cnt_i, 0, (size_t)N * 4, stream);
    hipMemsetAsync(cnt_t, 0, (size_t)N * 4, stream);
    hipMemsetAsync(ovfn, 0, 2 * 4, stream);
    hipMemsetAsync(gh, 0, (size_t)NB * 4, stream);

    k_hist<<<256, B, 0, stream>>>(int_dst, Ei, gh, NB, shift);
    k_scan_b<<<1, 1024, 0, stream>>>(gh, NB, boff, cur);
    k_scatter<<<blocks(((long long)Ei + EPT - 1) / EPT), B, 0, stream>>>(int_src, int_dst, Ei,
                                                                         shift, NB, cur, ebuf);
    k_fill3<<<NB, B, 0, stream>>>(ebuf, boff, NB, cnt_i, csr_i, Ci, ovf_i, &ovfn[0]);
    k_fill2<<<blocks(Et), B, 0, stream>>>(temp_src, temp_dst, Et, cnt_t, csr_t, Ct, ovf_t, &ovfn[1]);
    k_pad_x<<<blocks((long long)N * 8), B, 0, stream>>>(x_stroke, x8, N);

    k_layer_head<<<blocks((long long)N * 64), B, 0, stream>>>(
        x8, csr_i, cnt_i, Ci, csr_t, cnt_t, Ct, ovf_i, ovf_t, ovfn, head_Wt, head_Wi, head_Wr,
        head_b, bufA, N);

    float* hin = bufA;
    float* hout = bufD;
    for (int i = 0; i < 3; ++i) {
        k_gather32<<<blocks((long long)N * 64), B, 0, stream>>>(
            hin, csr_i, cnt_i, Ci, csr_t, cnt_t, Ct, ovf_i, ovf_t, ovfn, agg, N);
        k_gemm_blk<<<blocks(N), B, 0, stream>>>(
            agg, hin, blk_Wt + (size_t)i * 32 * 32, blk_Wi + (size_t)i * 32 * 32,
            blk_Wr + (size_t)i * 32 * 32, blk_b + (size_t)i * 32, hout, N);
        float* t = hin; hin = hout; hout = t;
    }

    k_gather32<<<blocks((long long)N * 64), B, 0, stream>>>(
        hin, csr_i, cnt_i, Ci, csr_t, cnt_t, Ct, ovf_i, ovf_t, ovfn, agg, N);
    k_gemm_last<<<blocks(N), B, 0, stream>>>(agg, hin, last_Wt, last_Wi, last_Wr, last_b,
                                             last_proj, (float*)d_out, N);
}

// Round 9
// 629.322 us; speedup vs baseline: 5.0369x; 1.0814x over previous
//
#include <hip/hip_runtime.h>

// Hetero-GNN: 5 layers of relu(segsum_temp(x)@Wt + segmean_inter(x)@Wi + x@Wr + b)
// (aggregation commuted past the matmuls).
//
// R9: all 5 layers split into gather (wave per destination, asm MLP loads) +
// thread-per-node GEMM (weights wave-uniform -> scalar loads, O(1) per node).
// Inter CSR is now DENSE, built per 128-node bucket with LDS staging:
//   hist -> scan -> bucket-sorted ebuf scatter -> per-bucket {LDS count, scan,
//   place, coalesced write-out} -> rs[] offsets + csr[] dense.
// This kills k_fill3's 6.6x write amplification (84 MB for a 12.8 MB payload)
// and halves every gather's csr fetch. Temp relation (100k edges) keeps the
// cheap padded one-pass fill + overflow list.

#define VO 8192    // overflow list capacity (pairs), temp relation
#define EPT 16     // edges per thread in k_scatter
#define FCAP 10240 // staged edges per bucket in k_fill3 (40 KB LDS)

typedef float vf4 __attribute__((ext_vector_type(4)));

__device__ inline void f4add(float4& a, const float4& v) {
    a.x += v.x; a.y += v.y; a.z += v.z; a.w += v.w;
}

// ---------------- build: hist -> scan -> scatter -> dense fill ----------------

__global__ void k_hist(const int* __restrict__ dst, int E, int* __restrict__ gh,
                       int NB, int shift) {
    __shared__ int sh[1024];
    for (int j = threadIdx.x; j < NB; j += blockDim.x) sh[j] = 0;
    __syncthreads();
    for (int i = blockIdx.x * blockDim.x + threadIdx.x; i < E; i += gridDim.x * blockDim.x)
        atomicAdd(&sh[dst[i] >> shift], 1);
    __syncthreads();
    for (int j = threadIdx.x; j < NB; j += blockDim.x)
        if (sh[j]) atomicAdd(&gh[j], sh[j]);
}

__global__ void k_scan_b(const int* __restrict__ gh, int NB, int* __restrict__ boff,
                         int* __restrict__ cur) {
    __shared__ int sh[1024];
    int t = threadIdx.x;
    sh[t] = (t < NB) ? gh[t] : 0;
    __syncthreads();
    for (int off = 1; off < 1024; off <<= 1) {
        int v = (t >= off) ? sh[t - off] : 0;
        __syncthreads();
        sh[t] += v;
        __syncthreads();
    }
    if (t < NB) {
        int ex = t ? sh[t - 1] : 0;
        boff[t] = ex;
        cur[t] = ex;
    }
    if (t == 0) boff[NB] = sh[NB - 1];
}

__global__ void k_scatter(const int* __restrict__ src, const int* __restrict__ dst, int E,
                          int shift, int NB, int* __restrict__ cur, int2* __restrict__ ebuf) {
    __shared__ int lh[1024];
    __shared__ int lb[1024];
    int lo = blockIdx.x * (blockDim.x * EPT);
    for (int j = threadIdx.x; j < NB; j += blockDim.x) lh[j] = 0;
    __syncthreads();
    int s[EPT], d[EPT], rk[EPT];
#pragma unroll
    for (int u = 0; u < EPT; ++u) {
        int e = lo + u * blockDim.x + threadIdx.x;
        if (e < E) {
            s[u] = src[e];
            d[u] = dst[e];
            rk[u] = atomicAdd(&lh[d[u] >> shift], 1);
        }
    }
    __syncthreads();
    for (int j = threadIdx.x; j < NB; j += blockDim.x) {
        int c = lh[j];
        lb[j] = c ? atomicAdd(&cur[j], c) : 0;
    }
    __syncthreads();
#pragma unroll
    for (int u = 0; u < EPT; ++u) {
        int e = lo + u * blockDim.x + threadIdx.x;
        if (e < E) ebuf[lb[d[u] >> shift] + rk[u]] = make_int2(s[u], d[u]);
    }
}

// dense CSR fill: one block per 128-node bucket. Two streaming passes over the
// bucket's ebuf segment; LDS staging -> coalesced full-line csr writes.
__global__ __launch_bounds__(256) void k_fill3(const int2* __restrict__ ebuf,
                                               const int* __restrict__ boff, int NB,
                                               int* __restrict__ rs, int* __restrict__ csr,
                                               int N) {
    __shared__ int hist[128];
    __shared__ int offs[129];
    __shared__ int curl[128];
    __shared__ int stage[FCAP];
    int b = blockIdx.x;
    if (b >= NB) return;
    int lo = boff[b], hi = boff[b + 1];
    int cnt = hi - lo;
    int base = b << 7;
    int t = threadIdx.x;
    for (int i = t; i < 128; i += 256) { hist[i] = 0; curl[i] = 0; }
    __syncthreads();
    // pass 1: count
    for (int e = lo + t; e < hi; e += 256) {
        int2 sd = ebuf[e];
        atomicAdd(&hist[sd.y & 127], 1);
    }
    __syncthreads();
    if (t == 0) {
        int run = 0;
        for (int i = 0; i < 128; ++i) { offs[i] = run; run += hist[i]; }
        offs[128] = run;
    }
    __syncthreads();
    // rs offsets (exact; dst < N so nodes >= N have count 0)
    for (int i = t; i < 128; i += 256) {
        int g = base + i;
        if (g < N) rs[g] = lo + offs[i];
    }
    if (b == NB - 1 && t == 0) rs[N] = hi;
    // pass 2: place
    bool staged = (cnt <= FCAP);
    for (int e = lo + t; e < hi; e += 256) {
        int2 sd = ebuf[e];
        int dl = sd.y & 127;
        int p = offs[dl] + atomicAdd(&curl[dl], 1);
        if (staged) stage[p] = sd.x;
        else csr[lo + p] = sd.x;
    }
    __syncthreads();
    if (staged)
        for (int i = t; i < cnt; i += 256) csr[lo + i] = stage[i];
}

// temp relation (100k edges): padded one-pass fill
__global__ void k_fill2(const int* __restrict__ src, const int* __restrict__ dst, int E,
                        int* __restrict__ cnt, int* __restrict__ csr, int C,
                        int* __restrict__ ovf, int* __restrict__ ovf_n) {
    int i = blockIdx.x * blockDim.x + threadIdx.x;
    if (i >= E) return;
    int s = src[i];
    int d = dst[i];
    int slot = atomicAdd(&cnt[d], 1);
    if (slot < C) {
        csr[(size_t)d * C + slot] = s;
    } else {
        int p = atomicAdd(ovf_n, 1);
        if (p < VO) { ovf[2 * p] = d; ovf[2 * p + 1] = s; }
    }
}

__global__ void k_pad_x(const float* __restrict__ x, float* __restrict__ x8, int N) {
    int i = blockIdx.x * blockDim.x + threadIdx.x;
    if (i >= N * 8) return;
    int n = i >> 3, c = i & 7;
    x8[i] = (c < 6) ? x[n * 6 + c] : 0.0f;
}

// ---------------- gathers ----------------

template <int CHV, int U, bool MASK>
__device__ inline void g_grp(const float* __restrict__ x, int sv, int it0, int nb,
                             int q, int r, float4& acc) {
    const int R = 64 / CHV;
    int s[U];
    float4 v[U];
#pragma unroll
    for (int u = 0; u < U; ++u) s[u] = __shfl(sv, (it0 + u) * R + r, 64);
#pragma unroll
    for (int u = 0; u < U; ++u) v[u] = *(const float4*)(x + (size_t)s[u] * (CHV * 4) + q * 4);
#pragma unroll
    for (int u = 0; u < U; ++u) {
        if (MASK) {
            float m = ((it0 + u) * R + r < nb) ? 1.0f : 0.0f;
            acc.x = fmaf(m, v[u].x, acc.x);
            acc.y = fmaf(m, v[u].y, acc.y);
            acc.z = fmaf(m, v[u].z, acc.z);
            acc.w = fmaf(m, v[u].w, acc.w);
        } else {
            f4add(acc, v[u]);
        }
    }
}

template <int CHV, int U>
__device__ inline float4 gather_one(const float* __restrict__ x, const int* __restrict__ csr,
                                    size_t rowbase, int cnt_c, int lane, int q, int r) {
    const int R = 64 / CHV;
    float4 acc = make_float4(0.f, 0.f, 0.f, 0.f);
    for (int base = 0; base < cnt_c; base += 64) {
        int nb = min(64, cnt_c - base);
        int sv = (lane < nb) ? csr[rowbase + base + lane] : 0;
        int it = 0;
        while ((it + U) * R <= nb) {
            g_grp<CHV, U, false>(x, sv, it, nb, q, r, acc);
            it += U;
        }
        if (it * R < nb) g_grp<CHV, U, true>(x, sv, it, nb, q, r, acc);
    }
    return acc;
}

// 32-ch asm gather: 4 row loads in flight, ONE vmcnt(0).
__device__ inline float4 gather_asm4(const float* __restrict__ x, const int* __restrict__ csr,
                                     size_t rowbase, int cnt_c, int lane, int q, int r) {
    float4 acc = make_float4(0.f, 0.f, 0.f, 0.f);
    for (int base = 0; base < cnt_c; base += 64) {
        int nb = min(64, cnt_c - base);
        int sv = (lane < nb) ? csr[rowbase + base + lane] : 0;
        for (int it = 0; it * 8 < nb; it += 4) {
            int s0 = __shfl(sv, (it + 0) * 8 + r, 64);
            int s1 = __shfl(sv, (it + 1) * 8 + r, 64);
            int s2 = __shfl(sv, (it + 2) * 8 + r, 64);
            int s3 = __shfl(sv, (it + 3) * 8 + r, 64);
            const float* a0 = x + (size_t)s0 * 32 + q * 4;
            const float* a1 = x + (size_t)s1 * 32 + q * 4;
            const float* a2 = x + (size_t)s2 * 32 + q * 4;
            const float* a3 = x + (size_t)s3 * 32 + q * 4;
            vf4 v0, v1, v2, v3;
            asm volatile(
                "global_load_dwordx4 %0, %4, off\n\t"
                "global_load_dwordx4 %1, %5, off\n\t"
                "global_load_dwordx4 %2, %6, off\n\t"
                "global_load_dwordx4 %3, %7, off\n\t"
                "s_waitcnt vmcnt(0)"
                : "=&v"(v0), "=&v"(v1), "=&v"(v2), "=&v"(v3)
                : "v"(a0), "v"(a1), "v"(a2), "v"(a3)
                : "memory");
            if ((it + 4) * 8 <= nb) {
                acc.x += v0.x + v1.x + v2.x + v3.x;
                acc.y += v0.y + v1.y + v2.y + v3.y;
                acc.z += v0.z + v1.z + v2.z + v3.z;
                acc.w += v0.w + v1.w + v2.w + v3.w;
            } else {
                float m0 = ((it + 0) * 8 + r < nb) ? 1.0f : 0.0f;
                float m1 = ((it + 1) * 8 + r < nb) ? 1.0f : 0.0f;
                float m2 = ((it + 2) * 8 + r < nb) ? 1.0f : 0.0f;
                float m3 = ((it + 3) * 8 + r < nb) ? 1.0f : 0.0f;
                acc.x = fmaf(m0, v0.x, fmaf(m1, v1.x, fmaf(m2, v2.x, fmaf(m3, v3.x, acc.x))));
                acc.y = fmaf(m0, v0.y, fmaf(m1, v1.y, fmaf(m2, v2.y, fmaf(m3, v3.y, acc.y))));
                acc.z = fmaf(m0, v0.z, fmaf(m1, v1.z, fmaf(m2, v2.z, fmaf(m3, v3.z, acc.z))));
                acc.w = fmaf(m0, v0.w, fmaf(m1, v1.w, fmaf(m2, v2.w, fmaf(m3, v3.w, acc.w))));
            }
        }
    }
    return acc;
}

__device__ inline float4 gather_asm1(const float* __restrict__ x, const int* __restrict__ csr,
                                     size_t rowbase, int cnt_c, int lane, int q, int r) {
    float4 acc = make_float4(0.f, 0.f, 0.f, 0.f);
    for (int base = 0; base < cnt_c; base += 64) {
        int nb = min(64, cnt_c - base);
        int sv = (lane < nb) ? csr[rowbase + base + lane] : 0;
        for (int it = 0; it * 8 < nb; ++it) {
            int s0 = __shfl(sv, it * 8 + r, 64);
            const float* a0 = x + (size_t)s0 * 32 + q * 4;
            vf4 v0;
            asm volatile(
                "global_load_dwordx4 %0, %1, off\n\t"
                "s_waitcnt vmcnt(0)"
                : "=&v"(v0)
                : "v"(a0)
                : "memory");
            float m0 = (it * 8 + r < nb) ? 1.0f : 0.0f;
            acc.x = fmaf(m0, v0.x, acc.x);
            acc.y = fmaf(m0, v0.y, acc.y);
            acc.z = fmaf(m0, v0.z, acc.z);
            acc.w = fmaf(m0, v0.w, acc.w);
        }
    }
    return acc;
}

template <int CHV>
__device__ inline void ovf_add(const float* __restrict__ x, const int* __restrict__ ovf, int n,
                               int g, int q, int r, float4& acc) {
    for (int j = 0; j < n; ++j) {
        int d = ovf[2 * j];
        if (d == g) {
            int s = ovf[2 * j + 1];
            if (r == 0) f4add(acc, *(const float4*)(x + (size_t)s * (CHV * 4) + q * 4));
        }
    }
}

template <int CHV>
__device__ inline void reduce4(float4& a) {
#pragma unroll
    for (int st = CHV; st < 64; st <<= 1) {
        a.x += __shfl_xor(a.x, st, 64);
        a.y += __shfl_xor(a.y, st, 64);
        a.z += __shfl_xor(a.z, st, 64);
        a.w += __shfl_xor(a.w, st, 64);
    }
}

// head gather: 8ch padded rows -> agg8[n][16] = [aggi*inv | aggt]
__global__ __launch_bounds__(256) void k_gather_head(
    const float* __restrict__ x8, const int* __restrict__ csr_i, const int* __restrict__ rs,
    const int* __restrict__ csr_t, const int* __restrict__ cnt_t, int Ct,
    const int* __restrict__ ovf_t, const int* __restrict__ ovfn,
    float* __restrict__ agg8, int N) {
    int tid = blockIdx.x * blockDim.x + threadIdx.x;
    int g = tid >> 6;
    if (g >= N) return;
    int lane = threadIdx.x & 63;
    int q = lane & 1, r = lane >> 1;
    int e0 = rs[g], e1 = rs[g + 1];
    int cif = e1 - e0;
    int ctf = cnt_t[g], ct = min(ctf, Ct);
    float4 ai = gather_one<2, 2>(x8, csr_i, (size_t)e0, cif, lane, q, r);
    float4 at = gather_one<2, 1>(x8, csr_t, (size_t)g * Ct, ct, lane, q, r);
    if (ctf > Ct) ovf_add<2>(x8, ovf_t, min(ovfn[1], VO), g, q, r, at);
    reduce4<2>(ai);
    reduce4<2>(at);
    float inv = 1.0f / (float)max(cif, 1);
    if (r == 0) {
        *(float4*)(agg8 + (size_t)g * 16 + q * 4) =
            make_float4(ai.x * inv, ai.y * inv, ai.z * inv, ai.w * inv);
    } else if (r == 1) {
        *(float4*)(agg8 + (size_t)g * 16 + 8 + q * 4) = at;
    }
}

// hidden gather: 32ch rows -> agg[n][64] = [aggi*inv | aggt]
__global__ __launch_bounds__(256) void k_gather32(
    const float* __restrict__ hin, const int* __restrict__ csr_i, const int* __restrict__ rs,
    const int* __restrict__ csr_t, const int* __restrict__ cnt_t, int Ct,
    const int* __restrict__ ovf_t, const int* __restrict__ ovfn,
    float* __restrict__ agg, int N) {
    int tid = blockIdx.x * blockDim.x + threadIdx.x;
    int g = tid >> 6;
    if (g >= N) return;
    int lane = threadIdx.x & 63;
    int q = lane & 7, r = lane >> 3;
    int e0 = rs[g], e1 = rs[g + 1];
    int cif = e1 - e0;
    int ctf = cnt_t[g], ct = min(ctf, Ct);
    float4 ai = gather_asm4(hin, csr_i, (size_t)e0, cif, lane, q, r);
    float4 at = gather_asm1(hin, csr_t, (size_t)g * Ct, ct, lane, q, r);
    if (ctf > Ct) ovf_add<8>(hin, ovf_t, min(ovfn[1], VO), g, q, r, at);
    reduce4<8>(ai);
    reduce4<8>(at);
    float inv = 1.0f / (float)max(cif, 1);
    if (r == 0) {
        *(float4*)(agg + (size_t)g * 64 + q * 4) =
            make_float4(ai.x * inv, ai.y * inv, ai.z * inv, ai.w * inv);
    } else if (r == 1) {
        *(float4*)(agg + (size_t)g * 64 + 32 + q * 4) = at;
    }
}

// ---------------- per-node GEMM kernels (weights wave-uniform) ----------------

template <int OC>
__device__ inline void gemm_seg(const float* __restrict__ seg, const float* __restrict__ W,
                                float* acc) {
#pragma unroll 2
    for (int k4 = 0; k4 < 8; ++k4) {
        float4 a = ((const float4*)seg)[k4];
        float av[4] = {a.x, a.y, a.z, a.w};
#pragma unroll
        for (int i = 0; i < 4; ++i) {
            const float* Wk = W + (k4 * 4 + i) * OC;
#pragma unroll
            for (int c = 0; c < OC; ++c) acc[c] = fmaf(av[i], Wk[c], acc[c]);
        }
    }
}

__global__ __launch_bounds__(256) void k_gemm_head(
    const float* __restrict__ agg8, const float* __restrict__ x8,
    const float* __restrict__ Wt, const float* __restrict__ Wi, const float* __restrict__ Wr,
    const float* __restrict__ b, float* __restrict__ hout, int N) {
    int n = blockIdx.x * blockDim.x + threadIdx.x;
    if (n >= N) return;
    float acc[32];
#pragma unroll
    for (int c = 0; c < 32; ++c) acc[c] = b[c];
    float4 ai0 = ((const float4*)(agg8 + (size_t)n * 16))[0];
    float4 ai1 = ((const float4*)(agg8 + (size_t)n * 16))[1];
    float4 at0 = ((const float4*)(agg8 + (size_t)n * 16 + 8))[0];
    float4 at1 = ((const float4*)(agg8 + (size_t)n * 16 + 8))[1];
    float4 xv0 = ((const float4*)(x8 + (size_t)n * 8))[0];
    float4 xv1 = ((const float4*)(x8 + (size_t)n * 8))[1];
    float a_i[6] = {ai0.x, ai0.y, ai0.z, ai0.w, ai1.x, ai1.y};
    float a_t[6] = {at0.x, at0.y, at0.z, at0.w, at1.x, at1.y};
    float a_x[6] = {xv0.x, xv0.y, xv0.z, xv0.w, xv1.x, xv1.y};
#pragma unroll
    for (int k = 0; k < 6; ++k) {
        const float* Wtk = Wt + k * 32;
        const float* Wik = Wi + k * 32;
        const float* Wrk = Wr + k * 32;
#pragma unroll
        for (int c = 0; c < 32; ++c)
            acc[c] = fmaf(a_t[k], Wtk[c], fmaf(a_i[k], Wik[c], fmaf(a_x[k], Wrk[c], acc[c])));
    }
    float* O = hout + (size_t)n * 32;
#pragma unroll
    for (int c4 = 0; c4 < 8; ++c4)
        ((float4*)O)[c4] = make_float4(fmaxf(acc[c4 * 4 + 0], 0.f), fmaxf(acc[c4 * 4 + 1], 0.f),
                                       fmaxf(acc[c4 * 4 + 2], 0.f), fmaxf(acc[c4 * 4 + 3], 0.f));
}

__global__ __launch_bounds__(256) void k_gemm_blk(
    const float* __restrict__ agg, const float* __restrict__ hin,
    const float* __restrict__ Wt, const float* __restrict__ Wi, const float* __restrict__ Wr,
    const float* __restrict__ b, float* __restrict__ hout, int N) {
    int n = blockIdx.x * blockDim.x + threadIdx.x;
    if (n >= N) return;
    float acc[32];
#pragma unroll
    for (int c = 0; c < 32; ++c) acc[c] = b[c];
    const float* Ai = agg + (size_t)n * 64;
    const float* At = agg + (size_t)n * 64 + 32;
    const float* H = hin + (size_t)n * 32;
    gemm_seg<32>(At, Wt, acc);
    gemm_seg<32>(Ai, Wi, acc);
    gemm_seg<32>(H, Wr, acc);
    float* O = hout + (size_t)n * 32;
#pragma unroll
    for (int c4 = 0; c4 < 8; ++c4) {
        float4 hv = ((const float4*)H)[c4];
        ((float4*)O)[c4] = make_float4(fmaxf(acc[c4 * 4 + 0], 0.f) + hv.x,
                                       fmaxf(acc[c4 * 4 + 1], 0.f) + hv.y,
                                       fmaxf(acc[c4 * 4 + 2], 0.f) + hv.z,
                                       fmaxf(acc[c4 * 4 + 3], 0.f) + hv.w);
    }
}

__global__ __launch_bounds__(256) void k_gemm_last(
    const float* __restrict__ agg, const float* __restrict__ hin,
    const float* __restrict__ Wt, const float* __restrict__ Wi, const float* __restrict__ Wr,
    const float* __restrict__ b, const float* __restrict__ proj, float* __restrict__ out, int N) {
    int n = blockIdx.x * blockDim.x + threadIdx.x;
    if (n >= N) return;
    float acc[64];
#pragma unroll
    for (int c = 0; c < 64; ++c) acc[c] = b[c];
    const float* Ai = agg + (size_t)n * 64;
    const float* At = agg + (size_t)n * 64 + 32;
    const float* H = hin + (size_t)n * 32;
    gemm_seg<64>(At, Wt, acc);
    gemm_seg<64>(Ai, Wi, acc);
    gemm_seg<64>(H, Wr, acc);
#pragma unroll
    for (int c = 0; c < 64; ++c) acc[c] = fmaxf(acc[c], 0.f);
    gemm_seg<64>(H, proj, acc);
    float* O = out + (size_t)n * 64;
#pragma unroll
    for (int c4 = 0; c4 < 16; ++c4)
        ((float4*)O)[c4] = make_float4(acc[c4 * 4 + 0], acc[c4 * 4 + 1],
                                       acc[c4 * 4 + 2], acc[c4 * 4 + 3]);
}

// ---------------- launch ----------------

static inline size_t align256(size_t x) { return (x + 255) & ~(size_t)255; }

extern "C" void kernel_launch(void* const* d_in, const int* in_sizes, int n_in,
                              void* d_out, int out_size, void* d_ws, size_t ws_size,
                              hipStream_t stream) {
    const float* x_stroke = (const float*)d_in[0];
    const int* ei_temp = (const int*)d_in[1];
    const int* ei_inter = (const int*)d_in[2];
    const float* head_Wt = (const float*)d_in[3];
    const float* head_Wi = (const float*)d_in[4];
    const float* head_Wr = (const float*)d_in[5];
    const float* head_b = (const float*)d_in[6];
    const float* blk_Wt = (const float*)d_in[7];
    const float* blk_Wi = (const float*)d_in[8];
    const float* blk_Wr = (const float*)d_in[9];
    const float* blk_b = (const float*)d_in[10];
    const float* last_Wt = (const float*)d_in[11];
    const float* last_Wi = (const float*)d_in[12];
    const float* last_Wr = (const float*)d_in[13];
    const float* last_b = (const float*)d_in[14];
    const float* last_proj = (const float*)d_in[15];

    const int N = in_sizes[0] / 6;
    const int Et = in_sizes[1] / 2;
    const int Ei = in_sizes[2] / 2;

    const int* temp_src = ei_temp;
    const int* temp_dst = ei_temp + Et;
    const int* int_src = ei_inter;
    const int* int_dst = ei_inter + Ei;

    const int shift = 7;                      // 128-node buckets
    const int NB = ((N - 1) >> shift) + 1;    // assumes N <= 131072

    char* p = (char*)d_ws;
    size_t off = 0;
    auto carve = [&](size_t bytes) {
        char* r = p + off;
        off = align256(off + bytes);
        return r;
    };
    int* cnt_t = (int*)carve((size_t)N * 4);
    int* ovfn = (int*)carve(2 * 4);
    int* ovf_t = (int*)carve((size_t)VO * 8);
    int* gh = (int*)carve((size_t)NB * 4);
    int* boff = (int*)carve((size_t)(NB + 1) * 4);
    int* cur = (int*)carve((size_t)NB * 4);
    int* rs = (int*)carve((size_t)(N + 1) * 4);
    float* x8 = (float*)carve((size_t)N * 8 * 4);
    float* bufA = (float*)carve((size_t)N * 32 * 4);
    float* bufD = (float*)carve((size_t)N * 32 * 4);
    float* agg = (float*)carve((size_t)N * 64 * 4);   // also holds agg8 [N,16]
    int2* ebuf = (int2*)carve((size_t)Ei * 8);
    int* csr_i = (int*)carve((size_t)Ei * 4);         // dense
    const int Ct = 16;
    int* csr_t = (int*)carve((size_t)N * Ct * 4);
    (void)ws_size;

    const int B = 256;
    auto blocks = [&](long long work) { return (int)((work + B - 1) / B); };

    hipMemsetAsync(cnt_t, 0, (size_t)N * 4, stream);
    hipMemsetAsync(ovfn, 0, 2 * 4, stream);
    hipMemsetAsync(gh, 0, (size_t)NB * 4, stream);

    k_hist<<<256, B, 0, stream>>>(int_dst, Ei, gh, NB, shift);
    k_scan_b<<<1, 1024, 0, stream>>>(gh, NB, boff, cur);
    k_scatter<<<blocks(((long long)Ei + EPT - 1) / EPT), B, 0, stream>>>(int_src, int_dst, Ei,
                                                                         shift, NB, cur, ebuf);
    k_fill3<<<NB, B, 0, stream>>>(ebuf, boff, NB, rs, csr_i, N);
    k_fill2<<<blocks(Et), B, 0, stream>>>(temp_src, temp_dst, Et, cnt_t, csr_t, Ct, ovf_t, &ovfn[1]);
    k_pad_x<<<blocks((long long)N * 8), B, 0, stream>>>(x_stroke, x8, N);

    // head
    k_gather_head<<<blocks((long long)N * 64), B, 0, stream>>>(
        x8, csr_i, rs, csr_t, cnt_t, Ct, ovf_t, ovfn, agg, N);
    k_gemm_head<<<blocks(N), B, 0, stream>>>(agg, x8, head_Wt, head_Wi, head_Wr, head_b, bufA, N);

    // 3 hidden residual blocks
    float* hin = bufA;
    float* hout = bufD;
    for (int i = 0; i < 3; ++i) {
        k_gather32<<<blocks((long long)N * 64), B, 0, stream>>>(
            hin, csr_i, rs, csr_t, cnt_t, Ct, ovf_t, ovfn, agg, N);
        k_gemm_blk<<<blocks(N), B, 0, stream>>>(
            agg, hin, blk_Wt + (size_t)i * 32 * 32, blk_Wi + (size_t)i * 32 * 32,
            blk_Wr + (size_t)i * 32 * 32, blk_b + (size_t)i * 32, hout, N);
        float* t = hin; hin = hout; hout = t;
    }

    // last
    k_gather32<<<blocks((long long)N * 64), B, 0, stream>>>(
        hin, csr_i, rs, csr_t, cnt_t, Ct, ovf_t, ovfn, agg, N);
    k_gemm_last<<<blocks(N), B, 0, stream>>>(agg, hin, last_Wt, last_Wi, last_Wr, last_b,
                                             last_proj, (float*)d_out, N);
}